// Round 16
// baseline (977.154 us; speedup 1.0000x reference)
//
#include <hip/hip_runtime.h>
#include <hip/hip_bf16.h>
#include <math.h>

// ---------------------------------------------------------------------------
// MoE trading transformer forward, MI355X/gfx950.
// B=16 S=512 F_IN=46 D=256 H=8 (dh=32) L=6 E=8 DFF=1024 OUT=3.
// R23: base = R22 (948.98us best). scatter_route eliminated: proj_gate_ln
// compacts tokens directly into fixed-capacity per-(slot,expert) segments
// via one reservation atomic per (slot,expert) per block (routing is
// permutation-invariant within a segment). A 1-block route_build makes the
// tile->(expert,base) table + pads segment tails. ln_kernel zeros gcnt for
// the next layer. hid stays compact-by-tile (w1/w2 GEMM indexing unchanged).
// ---------------------------------------------------------------------------

typedef __bf16 bf16;
typedef __bf16 bf16x8 __attribute__((ext_vector_type(8)));
typedef __bf16 bf16x4 __attribute__((ext_vector_type(4)));
typedef float f32x4 __attribute__((ext_vector_type(4)));

#define NIN 41

#define GLOAD_LDS(g, l)                                                    \
    __builtin_amdgcn_global_load_lds(                                      \
        (const __attribute__((address_space(1))) void*)(g),                \
        (__attribute__((address_space(3))) void*)(l), 16, 0, 0)

struct InTab {
    const void* src[NIN];
    unsigned off[NIN];
    unsigned n[NIN];
};

__device__ __forceinline__ float gelu_exact(float x) {
    return 0.5f * x * (1.0f + erff(x * 0.70710678118654752f));
}

// exact-GELU via Abramowitz-Stegun 7.1.26 erf (|err| < 1.5e-7).
__device__ __forceinline__ float gelu_fast(float x) {
    const float u = fabsf(x) * 0.70710678118654752f;
    const float t = 1.0f / (1.0f + 0.3275911f * u);
    const float p = t * (0.254829592f + t * (-0.284496736f + t * (1.421413741f +
                    t * (-1.453152027f + t * 1.061405429f))));
    const float er = 1.0f - p * __builtin_exp2f(-u * u * 1.4426950408889634f);
    const float s = (x >= 0.0f) ? er : -er;
    return 0.5f * x * (1.0f + s);
}

// ---------------------------------------------------------------------------
// Dtype sniffer (f32 vs bf16 storage). flag: 1=bf16, 0=f32.
// ---------------------------------------------------------------------------
__global__ void sniff_kernel(const unsigned* __restrict__ xw, int* __restrict__ flag) {
    __shared__ int cnt;
    if (threadIdx.x == 0) cnt = 0;
    __syncthreads();
    const unsigned w = xw[threadIdx.x];
    const unsigned ex = (w >> 7) & 0xFFu;
    if (ex >= 107u && ex <= 133u) atomicAdd(&cnt, 1);
    __syncthreads();
    if (threadIdx.x == 0) *flag = (cnt >= 192) ? 1 : 0;
}

__global__ __launch_bounds__(256) void convert_kernel(
    InTab tab, bf16* __restrict__ dst_base, const int* __restrict__ flag) {
    const unsigned g0 = blockIdx.x * 1024u;
    int inp = 0;
#pragma unroll
    for (int i = 1; i < NIN; i++)
        if (g0 >= tab.off[i]) inp = i;
    const unsigned n = tab.n[inp];
    const unsigned i0 = g0 - tab.off[inp] + threadIdx.x * 4u;
    if (i0 >= n) return;
    const int isbf = *flag;
    bf16* dst = dst_base + tab.off[inp];
    const unsigned end = (i0 + 4u > n) ? n : i0 + 4u;
    if (isbf) {
        const unsigned short* s = (const unsigned short*)tab.src[inp];
        for (unsigned i = i0; i < end; i++) ((unsigned short*)dst)[i] = s[i];
    } else {
        const float* s = (const float*)tab.src[inp];
        for (unsigned i = i0; i < end; i++) dst[i] = (bf16)s[i];
    }
}

// aux folded in here (reads the 48 per-layer/expert softmax sums directly).
__global__ void out_convert_kernel(const float* __restrict__ st,
                                   const float* __restrict__ auxsums,
                                   void* __restrict__ out,
                                   const int* __restrict__ flag) {
    const int i = threadIdx.x;
    if (i >= 65) return;
    float v;
    if (i == 64) {
        float tot = 0.0f;
        for (int l = 0; l < 6; l++)
            for (int e = 0; e < 8; e++) {
                const float mn = auxsums[l * 8 + e] * (1.0f / 8192.0f);
                tot += 8.0f * mn * mn;
            }
        v = tot;
    } else {
        v = st[i];
    }
    if (*flag) ((bf16*)out)[i] = (bf16)v;
    else       ((float*)out)[i] = v;
}

// swizzled LDS element index for (tile-local row r, col-chunk c) [chunks of 8 bf16]
#define SWZ(r, c) (((r) * 8 + ((c) ^ ((r) & 7))) * 8)

// ---------------------------------------------------------------------------
// Dense MFMA GEMM, async-staged + swizzled:  C = A @ W'^T + bias', where
// W'/bias'/C columns start at global column ncol_off. VTOUT: global cols
// >= 512 go transposed to vT[b][h][d][s] (bf16x4 stores).
// ---------------------------------------------------------------------------
template <int BM, int BN, int WM, int WN, bool VTOUT>
__global__ __launch_bounds__(256) void gemm_bt(
    const bf16* __restrict__ A, const bf16* __restrict__ W,
    const bf16* __restrict__ bias, bf16* __restrict__ C,
    int M, int N, int K, bf16* __restrict__ vT, int ncol_off) {
    constexpr int BK = 64;
    __shared__ alignas(16) bf16 smem[BM * BK + BN * BK];
    bf16* As = smem;
    bf16* Ws = smem + BM * BK;
    const int bm0 = blockIdx.x * BM;
    const int bn0g = blockIdx.y * BN + ncol_off;      // global column base
    const int tid = threadIdx.x;
    const int wave = tid >> 6, lane = tid & 63;
    constexpr int WCOLS = BN / WN;
    const int wm0 = (wave / WCOLS) * WM, wn0 = (wave % WCOLS) * WN;
    constexpr int MT = WM / 16, NT = WN / 16;
    f32x4 acc[MT][NT] = {};
    const int frow = lane & 15, fquad = lane >> 4;

    constexpr int AIT = BM / 32, BIT = BN / 32;
    const bf16* ag[AIT];
    const bf16* bg[BIT];
    unsigned al[AIT], bl[BIT];
#pragma unroll
    for (int i = 0; i < AIT; i++) {
        const int d = wave * (BM * 2) + i * 64 + lane;
        const int r = d >> 3, c = ((d & 7) ^ (r & 7)) * 8;
        ag[i] = A + (size_t)(bm0 + r) * K + c;
        al[i] = (unsigned)(wave * (BM * 2) + i * 64) * 8u;
    }
#pragma unroll
    for (int i = 0; i < BIT; i++) {
        const int d = wave * (BN * 2) + i * 64 + lane;
        const int r = d >> 3, c = ((d & 7) ^ (r & 7)) * 8;
        bg[i] = W + (size_t)(bn0g + r) * K + c;
        bl[i] = (unsigned)(wave * (BN * 2) + i * 64) * 8u;
    }

    for (int k0 = 0; k0 < K; k0 += BK) {
#pragma unroll
        for (int i = 0; i < AIT; i++) GLOAD_LDS(ag[i] + k0, &As[al[i]]);
#pragma unroll
        for (int i = 0; i < BIT; i++) GLOAD_LDS(bg[i] + k0, &Ws[bl[i]]);
        __syncthreads();
#pragma unroll
        for (int ks = 0; ks < BK / 32; ks++) {
            bf16x8 af[MT], bfr[NT];
#pragma unroll
            for (int mt = 0; mt < MT; mt++) {
                const int r = wm0 + mt * 16 + frow;
                af[mt] = *(const bf16x8*)&As[SWZ(r, ks * 4 + fquad)];
            }
#pragma unroll
            for (int nt = 0; nt < NT; nt++) {
                const int r = wn0 + nt * 16 + frow;
                bfr[nt] = *(const bf16x8*)&Ws[SWZ(r, ks * 4 + fquad)];
            }
#pragma unroll
            for (int mt = 0; mt < MT; mt++)
#pragma unroll
                for (int nt = 0; nt < NT; nt++)
                    acc[mt][nt] = __builtin_amdgcn_mfma_f32_16x16x32_bf16(
                        af[mt], bfr[nt], acc[mt][nt], 0, 0, 0);
        }
        __syncthreads();
    }

    if (VTOUT && bn0g >= 512) {
        // V path: 4 consecutive s per lane -> one bf16x4 store.
#pragma unroll
        for (int mt = 0; mt < MT; mt++)
#pragma unroll
            for (int nt = 0; nt < NT; nt++) {
                const int gn = bn0g + wn0 + nt * 16 + frow;
                const float bv = (float)bias[gn];
                bf16x4 o4;
#pragma unroll
                for (int r = 0; r < 4; r++) o4[r] = (bf16)(acc[mt][nt][r] + bv);
                const int gm0 = bm0 + wm0 + mt * 16 + fquad * 4;
                const int d = gn - 512;
                *(bf16x4*)&vT[((size_t)((gm0 >> 9) * 8 + (d >> 5)) * 32 + (d & 31)) * 512 +
                              (gm0 & 511)] = o4;
            }
    } else {
        // C path: stage tile in LDS (reuse smem), then coalesced bf16x8 stores.
        bf16* Cs = smem;
#pragma unroll
        for (int mt = 0; mt < MT; mt++)
#pragma unroll
            for (int nt = 0; nt < NT; nt++) {
                const int cl = wn0 + nt * 16 + frow;
                const float bv = (float)bias[bn0g + cl];
#pragma unroll
                for (int r = 0; r < 4; r++)
                    Cs[(wm0 + mt * 16 + fquad * 4 + r) * BN + cl] =
                        (bf16)(acc[mt][nt][r] + bv);
            }
        __syncthreads();
        constexpr int CPR = BN / 8;                       // chunks per row
        constexpr int CH = (BM * BN) / (256 * 8);         // chunks per thread
#pragma unroll
        for (int i = 0; i < CH; i++) {
            const int ch = tid + i * 256;
            const int row = ch / CPR;
            const int col = (ch % CPR) * 8;
            *(bf16x8*)&C[(size_t)(bm0 + row) * N + bn0g + col] =
                *(const bf16x8*)&Cs[row * BN + col];
        }
    }
}

// ---------------------------------------------------------------------------
// Route build: 1 block. From gcnt[16] build per-slot tile tables
// (tile_ex = expert, tile_base = segment offset) and pad segment tails.
// list layout: [slot][expert][8192].
// ---------------------------------------------------------------------------
__global__ __launch_bounds__(256) void route_build_kernel(
    const int* __restrict__ gcnt, int* __restrict__ ntiles,
    int* __restrict__ tile_ex, int* __restrict__ tile_base,
    int* __restrict__ list, float* __restrict__ lw) {
    __shared__ int cnt[16];
    const int t = threadIdx.x;
    if (t < 16) cnt[t] = gcnt[t];
    __syncthreads();
    if (t < 2) {
        const int slot = t;
        int T = 0;
        for (int e = 0; e < 8; e++) {
            const int c = cnt[slot * 8 + e];
            const int nt = (c + 63) >> 6;
            for (int k = 0; k < nt; k++) {
                tile_ex[slot * 160 + T] = e;
                tile_base[slot * 160 + T] = e * 8192 + k * 64;
                T++;
            }
        }
        ntiles[slot] = T;
    }
    // pad segment tails (<= 63 per segment) with token 8192 / weight 0
    for (int i = t; i < 1024; i += 256) {
        const int seg = i >> 6, j = i & 63;
        const int c = cnt[seg];
        const int rc = (c + 63) & ~63;
        const int p = c + j;
        if (p < rc) {
            const int slot = seg >> 3, e = seg & 7;
            list[slot * 65536 + e * 8192 + p] = 8192;
            lw[slot * 65536 + e * 8192 + p] = 0.0f;
        }
    }
}

// ---------------------------------------------------------------------------
// MoE w1 (both slots, one launch): hid{slot}[i] = GELU(h[list[i]] @ w1_e^T + b1_e)
// BM=64, BN=128 -> grid (288, 8). hid compact-by-tile. LDS 24 KB.
// ---------------------------------------------------------------------------
__global__ __launch_bounds__(256) void gemm_moe_w1(
    const bf16* __restrict__ A, const bf16* __restrict__ Wb,
    const bf16* __restrict__ biasb, bf16* __restrict__ hid0,
    bf16* __restrict__ hid1, const int* __restrict__ list,
    const int* __restrict__ tile_ex, const int* __restrict__ tile_base,
    const int* __restrict__ ntiles) {
    constexpr int BM = 64, BN = 128, BK = 64;
    constexpr int N = 1024, K = 256;
    const int slot = (blockIdx.x >= 144) ? 1 : 0;
    const int xi = (int)blockIdx.x - slot * 144;
    if (xi >= ntiles[slot]) return;
    __shared__ alignas(16) bf16 smem[BM * BK + BN * BK];   // 24 KB
    bf16* As = smem;
    bf16* Ws = smem + BM * BK;
    const int* mylist = list + slot * 65536;
    const int e = tile_ex[slot * 160 + xi];
    const int tb = tile_base[slot * 160 + xi];
    const bf16* W = Wb + (size_t)e * N * K;
    const bf16* bias = biasb + e * N;
    bf16* C = slot ? hid1 : hid0;
    const int bm0 = xi * BM, bn0 = blockIdx.y * BN;
    const int tid = threadIdx.x;
    const int wave = tid >> 6, lane = tid & 63;
    const int wm0 = (wave >> 1) * 32, wn0 = (wave & 1) * 64;  // 2x2, 32x64/wave
    constexpr int MT = 2, NT = 4;
    f32x4 acc[MT][NT] = {};
    const int frow = lane & 15, fquad = lane >> 4;

    const bf16* ag[2];
    const bf16* bg[4];
    unsigned al[2], bl[4];
#pragma unroll
    for (int i = 0; i < 2; i++) {
        const int d = wave * 128 + i * 64 + lane;
        const int r = d >> 3, c = ((d & 7) ^ (r & 7)) * 8;
        ag[i] = A + (size_t)mylist[tb + r] * K + c;
        al[i] = (unsigned)(wave * 128 + i * 64) * 8u;
    }
#pragma unroll
    for (int i = 0; i < 4; i++) {
        const int d = wave * 256 + i * 64 + lane;
        const int r = d >> 3, c = ((d & 7) ^ (r & 7)) * 8;
        bg[i] = W + (size_t)(bn0 + r) * K + c;
        bl[i] = (unsigned)(wave * 256 + i * 64) * 8u;
    }

    for (int k0 = 0; k0 < K; k0 += BK) {
#pragma unroll
        for (int i = 0; i < 2; i++) GLOAD_LDS(ag[i] + k0, &As[al[i]]);
#pragma unroll
        for (int i = 0; i < 4; i++) GLOAD_LDS(bg[i] + k0, &Ws[bl[i]]);
        __syncthreads();
#pragma unroll
        for (int ks = 0; ks < 2; ks++) {
            bf16x8 af[MT], bfr[NT];
#pragma unroll
            for (int mt = 0; mt < MT; mt++) {
                const int r = wm0 + mt * 16 + frow;
                af[mt] = *(const bf16x8*)&As[SWZ(r, ks * 4 + fquad)];
            }
#pragma unroll
            for (int nt = 0; nt < NT; nt++) {
                const int r = wn0 + nt * 16 + frow;
                bfr[nt] = *(const bf16x8*)&Ws[SWZ(r, ks * 4 + fquad)];
            }
#pragma unroll
            for (int mt = 0; mt < MT; mt++)
#pragma unroll
                for (int nt = 0; nt < NT; nt++)
                    acc[mt][nt] = __builtin_amdgcn_mfma_f32_16x16x32_bf16(
                        af[mt], bfr[nt], acc[mt][nt], 0, 0, 0);
        }
        __syncthreads();
    }

    // epilogue: GELU -> LDS tile (64x128, 16 KB fits in smem) -> coalesced
    {
        bf16* Cs = smem;
#pragma unroll
        for (int mt = 0; mt < MT; mt++)
#pragma unroll
            for (int nt = 0; nt < NT; nt++) {
                const int cl = wn0 + nt * 16 + frow;
                const float bv = (float)bias[bn0 + cl];
#pragma unroll
                for (int r = 0; r < 4; r++)
                    Cs[(wm0 + mt * 16 + fquad * 4 + r) * BN + cl] =
                        (bf16)gelu_fast(acc[mt][nt][r] + bv);
            }
        __syncthreads();
#pragma unroll
        for (int i = 0; i < 4; i++) {
            const int ch = tid + i * 256;
            const int row = ch >> 4;            // 16 chunks per 128-col row
            const int col = (ch & 15) * 8;
            *(bf16x8*)&C[(size_t)(bm0 + row) * N + bn0 + col] =
                *(const bf16x8*)&Cs[row * BN + col];
        }
    }
}

// ---------------------------------------------------------------------------
// MoE w2, both slots in one launch (disjoint outputs moe0/moe1):
// moe{slot}[list[i]] = lw[i]*(hid{slot}[i] @ w2_e^T + b2_e)
// BM=64, BN=64 -> grid (288, 4). hid compact-by-tile. LDS 16 KB.
// ---------------------------------------------------------------------------
__global__ __launch_bounds__(256) void gemm_moe_w2(
    const bf16* __restrict__ hid0, const bf16* __restrict__ hid1,
    const bf16* __restrict__ Wb, const bf16* __restrict__ biasb,
    bf16* __restrict__ moe0, bf16* __restrict__ moe1,
    const int* __restrict__ list, const float* __restrict__ lw,
    const int* __restrict__ tile_ex, const int* __restrict__ tile_base,
    const int* __restrict__ ntiles) {
    constexpr int BM = 64, BN = 64, BK = 64;
    constexpr int N = 256, K = 1024;
    const int slot = (blockIdx.x >= 144) ? 1 : 0;
    const int xi = (int)blockIdx.x - slot * 144;
    if (xi >= ntiles[slot]) return;
    __shared__ alignas(16) bf16 smem[BM * BK + BN * BK];   // 16 KB
    bf16* As = smem;
    bf16* Ws = smem + BM * BK;
    const bf16* A = slot ? hid1 : hid0;
    bf16* C = slot ? moe1 : moe0;
    const int* mylist = list + slot * 65536;
    const float* mylw = lw + slot * 65536;
    const int e = tile_ex[slot * 160 + xi];
    const int tb = tile_base[slot * 160 + xi];
    const bf16* W = Wb + (size_t)e * N * K;
    const bf16* bias = biasb + e * N;
    const int bm0 = xi * BM, bn0 = blockIdx.y * BN;
    const int tid = threadIdx.x;
    const int wave = tid >> 6, lane = tid & 63;
    const int wm0 = wave * 16;                 // 4 waves, 16x64 each
    constexpr int NT = 4;
    f32x4 acc[NT] = {};
    const int frow = lane & 15, fquad = lane >> 4;

    const bf16* ag[2];
    const bf16* bg[2];
    unsigned al[2], bl[2];
#pragma unroll
    for (int i = 0; i < 2; i++) {
        const int d = wave * 128 + i * 64 + lane;
        const int r = d >> 3, c = ((d & 7) ^ (r & 7)) * 8;
        ag[i] = A + (size_t)(bm0 + r) * K + c;
        al[i] = (unsigned)(wave * 128 + i * 64) * 8u;
        bg[i] = W + (size_t)(bn0 + r) * K + c;
        bl[i] = al[i];
    }

    for (int k0 = 0; k0 < K; k0 += BK) {
#pragma unroll
        for (int i = 0; i < 2; i++) GLOAD_LDS(ag[i] + k0, &As[al[i]]);
#pragma unroll
        for (int i = 0; i < 2; i++) GLOAD_LDS(bg[i] + k0, &Ws[bl[i]]);
        __syncthreads();
#pragma unroll
        for (int ks = 0; ks < 2; ks++) {
            bf16x8 af, bfr[NT];
            af = *(const bf16x8*)&As[SWZ(wm0 + frow, ks * 4 + fquad)];
#pragma unroll
            for (int nt = 0; nt < NT; nt++) {
                const int r = nt * 16 + frow;
                bfr[nt] = *(const bf16x8*)&Ws[SWZ(r, ks * 4 + fquad)];
            }
#pragma unroll
            for (int nt = 0; nt < NT; nt++)
                acc[nt] = __builtin_amdgcn_mfma_f32_16x16x32_bf16(
                    af, bfr[nt], acc[nt], 0, 0, 0);
        }
        __syncthreads();
    }

    // epilogue: bias+lw -> LDS tile (64x64, 8 KB) -> coalesced scattered-row
    {
        bf16* Cs = smem;
        float lwv[4];
#pragma unroll
        for (int r = 0; r < 4; r++)
            lwv[r] = mylw[tb + wm0 + fquad * 4 + r];
#pragma unroll
        for (int nt = 0; nt < NT; nt++) {
            const int cl = nt * 16 + frow;
            const float bv = (float)bias[bn0 + cl];
#pragma unroll
            for (int r = 0; r < 4; r++)
                Cs[(wm0 + fquad * 4 + r) * BN + cl] =
                    (bf16)(lwv[r] * (acc[nt][r] + bv));
        }
        __syncthreads();
#pragma unroll
        for (int i = 0; i < 2; i++) {
            const int ch = tid + i * 256;
            const int row = ch >> 3;            // 8 chunks per 64-col row
            const int col = (ch & 7) * 8;
            *(bf16x8*)&C[(size_t)mylist[tb + row] * 256 + bn0 + col] =
                *(const bf16x8*)&Cs[row * BN + col];
        }
    }
}

// ---------------------------------------------------------------------------
// Input projection + positional encoding. grid 8192, block 256.
// ---------------------------------------------------------------------------
__global__ __launch_bounds__(256) void input_proj_kernel(
    const bf16* __restrict__ x, const bf16* __restrict__ w,
    const bf16* __restrict__ b, bf16* __restrict__ h) {
    const int m = blockIdx.x, t = threadIdx.x;
    __shared__ float xs[46];
    if (t < 46) xs[t] = (float)x[m * 46 + t];
    __syncthreads();
    float acc = (float)b[t];
#pragma unroll
    for (int k = 0; k < 46; k++) acc += xs[k] * (float)w[t * 46 + k];
    const int s = m & 511;
    const int i = t >> 1;
    const float dv = expf((float)(2 * i) * (-9.210340371976184f / 256.0f));
    const float ang = (float)s * dv;
    const float pe = (t & 1) ? cosf(ang) : sinf(ang);
    h[(size_t)m * 256 + t] = (bf16)(acc + pe);
}

// ---------------------------------------------------------------------------
// ln2: h = LN(h + moe0 + moe1)*s + b. bf16x8 loads, 2 tokens/wave. grid 1024.
// Block 0 also zeros gcnt[16] for the next layer's routing atomics.
// ---------------------------------------------------------------------------
__global__ __launch_bounds__(256) void ln_kernel(
    bf16* __restrict__ h, const bf16* __restrict__ a0,
    const bf16* __restrict__ a1, const bf16* __restrict__ s,
    const bf16* __restrict__ b, int* __restrict__ gcnt) {
    if (blockIdx.x == 0 && threadIdx.x < 16) gcnt[threadIdx.x] = 0;
    const int wv = threadIdx.x >> 6, lane = threadIdx.x & 63;
    const int m = blockIdx.x * 8 + wv * 2 + (lane >> 5);
    const int c0 = (lane & 31) * 8;
    const size_t off = (size_t)m * 256 + c0;
    bf16x8 hv = *(const bf16x8*)&h[off];
    bf16x8 av = *(const bf16x8*)&a0[off];
    bf16x8 bv2 = *(const bf16x8*)&a1[off];
    float x[8];
    float s1 = 0.0f, s2 = 0.0f;
#pragma unroll
    for (int j = 0; j < 8; j++) {
        x[j] = (float)hv[j] + (float)av[j] + (float)bv2[j];
        s1 += x[j];
        s2 += x[j] * x[j];
    }
#pragma unroll
    for (int msk = 1; msk < 32; msk <<= 1) {
        s1 += __shfl_xor(s1, msk, 64);
        s2 += __shfl_xor(s2, msk, 64);
    }
    const float mean = s1 * (1.0f / 256.0f);
    const float var = fmaxf(s2 * (1.0f / 256.0f) - mean * mean, 0.0f);
    const float inv = rsqrtf(var + 1e-5f);
    bf16x8 sv = *(const bf16x8*)&s[c0];
    bf16x8 bv = *(const bf16x8*)&b[c0];
    bf16x8 o;
#pragma unroll
    for (int j = 0; j < 8; j++)
        o[j] = (bf16)((x[j] - mean) * inv * (float)sv[j] + (float)bv[j]);
    *(bf16x8*)&h[off] = o;
}

// ---------------------------------------------------------------------------
// Fused: out-proj GEMM + residual + LN1 + h write + gate logits + top-2 +
// DIRECT routing compaction (block reserves ranges in fixed-capacity
// per-(slot,expert) segments via one atomic per segment) + aux sums.
// BM=16 -> grid 512 (2 blocks/CU). LDS ~48 KB. 4 waves, 1x4 layout.
// ---------------------------------------------------------------------------
__global__ __launch_bounds__(256) void proj_gate_ln_kernel(
    const bf16* __restrict__ A, const bf16* __restrict__ W,
    const bf16* __restrict__ bias, bf16* __restrict__ h,
    const bf16* __restrict__ lns, const bf16* __restrict__ lnb,
    const bf16* __restrict__ gw, const bf16* __restrict__ gb,
    int* __restrict__ gcnt, int* __restrict__ list, float* __restrict__ lw,
    float* __restrict__ aux_sums) {
    __shared__ alignas(16) bf16 As[16 * 64];     // 2 KB
    __shared__ alignas(16) bf16 Ws[256 * 64];    // 32 KB
    __shared__ alignas(16) bf16 hs[16 * 264];    // 8.25 KB, padded stride
    __shared__ alignas(16) bf16 gws[8 * 264];    // 4.1 KB
    __shared__ float rws1[4][16], rws2[4][16];
    __shared__ float meanv[16], invv[16];
    __shared__ float lg[128];                    // 16 tokens x 8 experts
    __shared__ int sh_hist[16];
    __shared__ int sel0[16], sel1[16];
    __shared__ float wt0[16], wt1[16];
    __shared__ int sh_base[16];
    __shared__ float sh_aux[8];

    const int bm0 = blockIdx.x * 16;
    const int tid = threadIdx.x;
    const int wave = tid >> 6, lane = tid & 63;
    const int wn0 = wave * 64;                   // 4 waves, 1x4; wm0 = 0
    const int frow = lane & 15, fquad = lane >> 4;
    f32x4 acc[4] = {};

    // A-stage: 128 chunks total; waves 0-1 stage 64 chunks each.
    const int da = (wave & 1) * 64 + lane;       // 0..127 for waves 0/1
    const int ra = da >> 3, ca = ((da & 7) ^ (ra & 7)) * 8;
    const bf16* ag = A + (size_t)(bm0 + ra) * 256 + ca;
    const unsigned al = (unsigned)((wave & 1) * 64) * 8u;
    // B-stage pointers (8 chunks/thread)
    const bf16* bg[8];
    unsigned bl[8];
#pragma unroll
    for (int i = 0; i < 8; i++) {
        const int d = wave * 512 + i * 64 + lane;
        const int r = d >> 3, c = ((d & 7) ^ (r & 7)) * 8;
        bg[i] = W + (size_t)r * 256 + c;
        bl[i] = (unsigned)(wave * 512 + i * 64) * 8u;
    }

    // stage h_old tile (16 rows, padded stride 264) + gate weights
    {
        const int rr = tid >> 4, ccb = (tid & 15) * 16;
        const bf16* src = &h[(size_t)(bm0 + rr) * 256 + ccb];
        bf16x8 v0 = *(const bf16x8*)&src[0];
        bf16x8 v1 = *(const bf16x8*)&src[8];
        bf16* dst = &hs[rr * 264 + ccb];
        *(bf16x8*)&dst[0] = v0;
        *(bf16x8*)&dst[8] = v1;
    }
    {
        const int e = tid >> 5, k = (tid & 31) * 8;
        *(bf16x8*)&gws[e * 264 + k] = *(const bf16x8*)&gw[e * 256 + k];
    }
    if (tid < 16) sh_hist[tid] = 0;
    if (tid < 8) sh_aux[tid] = 0.0f;

    for (int k0 = 0; k0 < 256; k0 += 64) {
        if (wave < 2) GLOAD_LDS(ag + k0, &As[al]);
#pragma unroll
        for (int i = 0; i < 8; i++) GLOAD_LDS(bg[i] + k0, &Ws[bl[i]]);
        __syncthreads();
#pragma unroll
        for (int ks = 0; ks < 2; ks++) {
            bf16x8 af, bfr[4];
            af = *(const bf16x8*)&As[SWZ(frow, ks * 4 + fquad)];
#pragma unroll
            for (int nt = 0; nt < 4; nt++)
                bfr[nt] = *(const bf16x8*)&Ws[SWZ(wn0 + nt * 16 + frow, ks * 4 + fquad)];
#pragma unroll
            for (int nt = 0; nt < 4; nt++)
                acc[nt] = __builtin_amdgcn_mfma_f32_16x16x32_bf16(
                    af, bfr[nt], acc[nt], 0, 0, 0);
        }
        __syncthreads();
    }

    // ---- x = proj + bias + h_old; per-row mean/var ----
    float s1v[4] = {}, s2v[4] = {};
#pragma unroll
    for (int nt = 0; nt < 4; nt++) {
        const int gn = wn0 + nt * 16 + frow;
        const float bv = (float)bias[gn];
#pragma unroll
        for (int r = 0; r < 4; r++) {
            const int row = fquad * 4 + r;
            const float x = acc[nt][r] + bv + (float)hs[row * 264 + gn];
            acc[nt][r] = x;
            s1v[r] += x;
            s2v[r] += x * x;
        }
    }
#pragma unroll
    for (int r = 0; r < 4; r++) {
#pragma unroll
        for (int m = 1; m < 16; m <<= 1) {
            s1v[r] += __shfl_xor(s1v[r], m, 64);
            s2v[r] += __shfl_xor(s2v[r], m, 64);
        }
    }
    if (frow == 0) {
#pragma unroll
        for (int r = 0; r < 4; r++) {
            const int row = fquad * 4 + r;
            rws1[wave][row] = s1v[r];
            rws2[wave][row] = s2v[r];
        }
    }
    __syncthreads();
    if (tid < 16) {
        const float a = rws1[0][tid] + rws1[1][tid] + rws1[2][tid] + rws1[3][tid];
        const float c2 = rws2[0][tid] + rws2[1][tid] + rws2[2][tid] + rws2[3][tid];
        const float mean = a * (1.0f / 256.0f);
        const float var = fmaxf(c2 * (1.0f / 256.0f) - mean * mean, 0.0f);
        meanv[tid] = mean;
        invv[tid] = rsqrtf(var + 1e-5f);
    }
    __syncthreads();

    // ---- LN output into hs ----
#pragma unroll
    for (int nt = 0; nt < 4; nt++) {
        const int gn = wn0 + nt * 16 + frow;
        const float sg = (float)lns[gn], bgn = (float)lnb[gn];
#pragma unroll
        for (int r = 0; r < 4; r++) {
            const int row = fquad * 4 + r;
            const float o = (acc[nt][r] - meanv[row]) * invv[row] * sg + bgn;
            hs[row * 264 + gn] = (bf16)o;
        }
    }
    __syncthreads();

    // ---- vectorized h writeback + gate logits ----
    {
        const int rr = tid >> 4, ccb = (tid & 15) * 16;
        bf16* dst = &h[(size_t)(bm0 + rr) * 256 + ccb];
        const bf16* src = &hs[rr * 264 + ccb];
        *(bf16x8*)&dst[0] = *(const bf16x8*)&src[0];
        *(bf16x8*)&dst[8] = *(const bf16x8*)&src[8];
    }
    if (tid < 128) {
        const int row = tid >> 3, e = tid & 7;
        float acg = (float)gb[e];
        for (int k = 0; k < 256; k += 8) {
            bf16x8 hv = *(const bf16x8*)&hs[row * 264 + k];
            bf16x8 wv = *(const bf16x8*)&gws[e * 264 + k];
#pragma unroll
            for (int q = 0; q < 8; q++) acg += (float)hv[q] * (float)wv[q];
        }
        lg[row * 8 + e] = acg;
    }
    __syncthreads();

    // ---- top-2 + aux per token ----
    if (tid < 16) {
        float l[8];
#pragma unroll
        for (int j = 0; j < 8; j++) l[j] = lg[tid * 8 + j];
        int i0 = 0;
#pragma unroll
        for (int j = 1; j < 8; j++)
            if (l[j] > l[i0]) i0 = j;
        int i1 = -1;
#pragma unroll
        for (int j = 0; j < 8; j++)
            if (j != i0 && (i1 < 0 || l[j] > l[i1])) i1 = j;
        const float p0 = 1.0f / (1.0f + expf(l[i1] - l[i0]));
        sel0[tid] = i0;  wt0[tid] = p0;
        sel1[tid] = i1;  wt1[tid] = 1.0f - p0;
        atomicAdd(&sh_hist[i0], 1);
        atomicAdd(&sh_hist[8 + i1], 1);
        const float mx = l[i0];
        float se = 0.0f;
#pragma unroll
        for (int j = 0; j < 8; j++) { l[j] = expf(l[j] - mx); se += l[j]; }
        const float si = 1.0f / se;
#pragma unroll
        for (int j = 0; j < 8; j++) atomicAdd(&sh_aux[j], l[j] * si);
    }
    __syncthreads();
    // reserve global ranges: one atomic per (slot,expert) with count>0
    if (tid < 16 && sh_hist[tid] > 0)
        sh_base[tid] = atomicAdd(&gcnt[tid], sh_hist[tid]);
    __syncthreads();
    // write tokens into reserved ranges (in-block rank by lower tid)
    if (tid < 16) {
        const int tok = bm0 + tid;
        const int e0 = sel0[tid], e1 = sel1[tid];
        int off0 = 0, off1 = 0;
        for (int j = 0; j < tid; j++) {
            if (sel0[j] == e0) off0++;
            if (sel1[j] == e1) off1++;
        }
        const int p0 = sh_base[e0] + off0;
        const int p1 = sh_base[8 + e1] + off1;
        list[e0 * 8192 + p0] = tok;
        lw[e0 * 8192 + p0] = wt0[tid];
        list[65536 + e1 * 8192 + p1] = tok;
        lw[65536 + e1 * 8192 + p1] = wt1[tid];
    }
    if (tid < 8) atomicAdd(&aux_sums[tid], sh_aux[tid]);
}

// ---------------------------------------------------------------------------
// Fused attention, one (b,h) x 32-query tile per block. grid (16,128).
// ---------------------------------------------------------------------------
__global__ __launch_bounds__(256) void attn_kernel(
    const bf16* __restrict__ qkv, const bf16* __restrict__ vT,
    bf16* __restrict__ aout) {
    __shared__ alignas(16) bf16 P[32][520];
    __shared__ float wsum[4][32];
    __shared__ float sinv[32];
    const int s0 = blockIdx.x * 32;
    const int b = blockIdx.y >> 3, hh = blockIdx.y & 7;
    const int tid = threadIdx.x, wave = tid >> 6, lane = tid & 63;
    const int frow = lane & 15, fquad = lane >> 4;
    const size_t base = (size_t)b * 512;
    const float CST = 0.25505654f;  // (1/sqrt(32)) * log2(e)

    bf16x8 qf[2];
#pragma unroll
    for (int mt = 0; mt < 2; mt++)
        qf[mt] = *(const bf16x8*)&qkv[(base + s0 + mt * 16 + frow) * 768 + hh * 32 + fquad * 8];
    float rsum[2][4] = {};
#pragma unroll
    for (int k8 = 0; k8 < 8; k8++) {
        const int key0 = (wave * 8 + k8) * 16;
        bf16x8 kf = *(const bf16x8*)&qkv[(base + key0 + frow) * 768 + 256 + hh * 32 + fquad * 8];
#pragma unroll
        for (int mt = 0; mt < 2; mt++) {
            f32x4 c = {};
            c = __builtin_amdgcn_mfma_f32_16x16x32_bf16(qf[mt], kf, c, 0, 0, 0);
#pragma unroll
            for (int r = 0; r < 4; r++) {
                const float e_ = __builtin_exp2f(fminf(c[r] * CST, 60.0f));
                P[mt * 16 + fquad * 4 + r][key0 + frow] = (bf16)e_;
                rsum[mt][r] += e_;
            }
        }
    }
#pragma unroll
    for (int mt = 0; mt < 2; mt++)
#pragma unroll
        for (int r = 0; r < 4; r++) {
#pragma unroll
            for (int m = 1; m < 16; m <<= 1)
                rsum[mt][r] += __shfl_xor(rsum[mt][r], m, 64);
        }
    if (frow == 0) {
#pragma unroll
        for (int mt = 0; mt < 2; mt++)
#pragma unroll
            for (int r = 0; r < 4; r++)
                wsum[wave][mt * 16 + fquad * 4 + r] = rsum[mt][r];
    }
    __syncthreads();
    if (tid < 32)
        sinv[tid] = 1.0f / (wsum[0][tid] + wsum[1][tid] + wsum[2][tid] + wsum[3][tid]);

    {
        const int mt = wave >> 1, nt = wave & 1;
        const bf16* vrow = &vT[((size_t)(b * 8 + hh) * 32 + nt * 16 + frow) * 512];
        f32x4 o = {};
#pragma unroll
        for (int ks = 0; ks < 16; ks++) {
            bf16x8 pf = *(const bf16x8*)&P[mt * 16 + frow][ks * 32 + fquad * 8];
            bf16x8 vf = *(const bf16x8*)&vrow[ks * 32 + fquad * 8];
            o = __builtin_amdgcn_mfma_f32_16x16x32_bf16(pf, vf, o, 0, 0, 0);
        }
        __syncthreads();
        const int r0 = mt * 16 + fquad * 4;
#pragma unroll
        for (int r = 0; r < 4; r++)
            aout[(base + s0 + r0 + r) * 256 + hh * 32 + nt * 16 + frow] =
                (bf16)(o[r] * sinv[r0 + r]);
    }
}

// ---------------------------------------------------------------------------
// Pooled attention: one block per (b,h). Computes its own q (16 last-token
// rows; the final qkv GEMM no longer produces Q). 4 waves split 512 keys;
// f32 softmax; output pattn f32 (16x256).
// ---------------------------------------------------------------------------
__global__ __launch_bounds__(256) void pooled_attn_kernel(
    const bf16* __restrict__ qkv, const bf16* __restrict__ vT,
    const bf16* __restrict__ hsrc, const bf16* __restrict__ wq,
    const bf16* __restrict__ qb, float* __restrict__ pattn) {
    __shared__ float p_lds[512];
    __shared__ float qs[32];
    __shared__ float wmax[4], wsum[4];
    const int b = blockIdx.x >> 3, hh = blockIdx.x & 7;
    const int tid = threadIdx.x, wave = tid >> 6, lane = tid & 63;
    const size_t base = (size_t)b * 512;
    const float scale = 0.17677669529663687f;

    // ---- q = h[last token] @ wq^T + bq, 8 threads per dim ----
    {
        const int d = tid >> 3, seg = tid & 7;
        const bf16* hr = &hsrc[(base + 511) * 256 + seg * 32];
        const bf16* wr = &wq[(size_t)(hh * 32 + d) * 256 + seg * 32];
        float a = 0.0f;
#pragma unroll
        for (int k = 0; k < 32; k += 8) {
            bf16x8 hv = *(const bf16x8*)&hr[k];
            bf16x8 wv = *(const bf16x8*)&wr[k];
#pragma unroll
            for (int q = 0; q < 8; q++) a += (float)hv[q] * (float)wv[q];
        }
#pragma unroll
        for (int m = 1; m < 8; m <<= 1) a += __shfl_xor(a, m, 64);
        if (seg == 0) qs[d] = a + (float)qb[hh * 32 + d];
    }
    __syncthreads();

    float s[2];
    float mx = -1e30f;
#pragma unroll
    for (int j = 0; j < 2; j++) {
        const int key = wave * 128 + j * 64 + lane;
        const bf16* kr = &qkv[(base + key) * 768 + 256 + hh * 32];
        float acc = 0.0f;
#pragma unroll
        for (int i = 0; i < 4; i++) {
            bf16x8 kv = *(const bf16x8*)&kr[i * 8];
#pragma unroll
            for (int q = 0; q < 8; q++) acc += qs[i * 8 + q] * (float)kv[q];
        }
        s[j] = acc * scale;
        mx = fmaxf(mx, s[j]);
    }
#pragma unroll
    for (int m = 1; m < 64; m <<= 1) mx = fmaxf(mx, __shfl_xor(mx, m, 64));
    if (lane == 0) wmax[wave] = mx;
    __syncthreads();
    const float bmx = fmaxf(fmaxf(wmax[0], wmax[1]), fmaxf(wmax[2], wmax[3]));
    float se = 0.0f;
#pragma unroll
    for (int j = 0; j < 2; j++) {
        s[j] = expf(s[j] - bmx);
        se += s[j];
        p_lds[wave * 128 + j * 64 + lane] = s[j];
    }
#pragma unroll
    for (int m = 1; m < 64; m <<= 1) se += __shfl_xor(se, m, 64);
    if (lane == 0) wsum[wave] = se;
    __syncthreads();
    const float inv = 1.0f / (wsum[0] + wsum[1] + wsum[2] + wsum[3]);

    // PV: 8 threads per output dim; each reads a contiguous 64-key V span.
    const int d = tid >> 3, seg = tid & 7;
    const bf16* vr = &vT[((size_t)(b * 8 + hh) * 32 + d) * 512 + seg * 64];
    const float* pp = &p_lds[seg * 64];
    float o = 0.0f;
#pragma unroll
    for (int i = 0; i < 64; i += 8) {
        bf16x8 vv = *(const bf16x8*)&vr[i];
#pragma unroll
        for (int q = 0; q < 8; q++) o += pp[i + q] * (float)vv[q];
    }
#pragma unroll
    for (int m = 1; m < 8; m <<= 1) o += __shfl_xor(o, m, 64);
    if (seg == 0) pattn[b * 256 + hh * 32 + d] = o * inv;
}

// ---------------------------------------------------------------------------
// Heads tail: action head on waves 0-1 (threads 0-127) CONCURRENT with
// profit head on waves 2-3 (threads 128-255). LN via per-wave shuffle reduce
// + one 8-float LDS exchange (1 barrier each). All __syncthreads are
// straight-line (reached by all 256 threads). grid 16, block 256.
// ---------------------------------------------------------------------------
__global__ __launch_bounds__(256) void heads_kernel(
    const float* __restrict__ pattn,
    const bf16* __restrict__ pout_w, const bf16* __restrict__ pout_b,
    const bf16* __restrict__ aw1, const bf16* __restrict__ ab1,
    const bf16* __restrict__ aln1s, const bf16* __restrict__ aln1b,
    const bf16* __restrict__ aw2, const bf16* __restrict__ ab2,
    const bf16* __restrict__ aln2s, const bf16* __restrict__ aln2b,
    const bf16* __restrict__ aw3, const bf16* __restrict__ ab3,
    const bf16* __restrict__ pw1, const bf16* __restrict__ pb1,
    const bf16* __restrict__ pln1s, const bf16* __restrict__ pln1b,
    const bf16* __restrict__ pw2, const bf16* __restrict__ pb2,
    const bf16* __restrict__ pln2s, const bf16* __restrict__ pln2b,
    const bf16* __restrict__ pw3, const bf16* __restrict__ pb3,
    float* __restrict__ out) {
    const int b = blockIdx.x, t = threadIdx.x;
    const int wave = t >> 6, lane = t & 63;
    __shared__ float pa_s[256], pool[256];
    __shared__ float bufa[128], buf2a[64];
    __shared__ float bufp[256], buf2p[128];
    __shared__ float red[8];

    pa_s[t] = pattn[b * 256 + t];
    __syncthreads();

    // ---- phase 0: pooled projection (all 256 threads) ----
    {
        float a = (float)pout_b[t];
        const bf16* wr = &pout_w[t * 256];
        for (int k = 0; k < 256; k += 8) {
            bf16x8 wv = *(const bf16x8*)&wr[k];
#pragma unroll
            for (int q = 0; q < 8; q++) a += pa_s[k + q] * (float)wv[q];
        }
        pool[t] = a;
    }
    __syncthreads();

    // ---- phase 1: first linears (action || profit) ----
    if (t < 128) {
        float a = (float)ab1[t];
        const bf16* wr = &aw1[t * 256];
        for (int k = 0; k < 256; k += 8) {
            bf16x8 wv = *(const bf16x8*)&wr[k];
#pragma unroll
            for (int q = 0; q < 8; q++) a += pool[k + q] * (float)wv[q];
        }
        bufa[t] = gelu_exact(a);
    } else {
        const int u = t - 128;
        float a0 = (float)pb1[u], a1 = (float)pb1[u + 128];
        const bf16* w0 = &pw1[u * 256];
        const bf16* w1 = &pw1[(u + 128) * 256];
        for (int k = 0; k < 256; k += 8) {
            bf16x8 wv0 = *(const bf16x8*)&w0[k];
            bf16x8 wv1 = *(const bf16x8*)&w1[k];
#pragma unroll
            for (int q = 0; q < 8; q++) {
                const float pv = pool[k + q];
                a0 += pv * (float)wv0[q];
                a1 += pv * (float)wv1[q];
            }
        }
        bufp[u] = a0;
        bufp[u + 128] = a1;
    }
    __syncthreads();

    // ---- phase 2: LN1 (action W=128 || profit W=256), shuffle reduce ----
    {
        float s1, s2;
        if (t < 128) {
            const float v = bufa[t];
            s1 = v; s2 = v * v;
        } else {
            const int u = t - 128;
            const float v0 = bufp[u], v1 = bufp[u + 128];
            s1 = v0 + v1; s2 = v0 * v0 + v1 * v1;
        }
#pragma unroll
        for (int m = 1; m < 64; m <<= 1) {
            s1 += __shfl_xor(s1, m, 64);
            s2 += __shfl_xor(s2, m, 64);
        }
        if (lane == 0) { red[wave * 2] = s1; red[wave * 2 + 1] = s2; }
    }
    __syncthreads();
    if (t < 128) {
        const float S1 = red[0] + red[2], S2 = red[1] + red[3];
        const float mean = S1 * (1.0f / 128.0f);
        const float var = fmaxf(S2 * (1.0f / 128.0f) - mean * mean, 0.0f);
        const float inv = rsqrtf(var + 1e-5f);
        bufa[t] = (bufa[t] - mean) * inv * (float)aln1s[t] + (float)aln1b[t];
    } else {
        const int u = t - 128;
        const float S1 = red[4] + red[6], S2 = red[5] + red[7];
        const float mean = S1 * (1.0f / 256.0f);
        const float var = fmaxf(S2 * (1.0f / 256.0f) - mean * mean, 0.0f);
        const float inv = rsqrtf(var + 1e-5f);
        bufp[u] = gelu_exact((bufp[u] - mean) * inv * (float)pln1s[u] + (float)pln1b[u]);
        bufp[u + 128] = gelu_exact((bufp[u + 128] - mean) * inv *
                                   (float)pln1s[u + 128] + (float)pln1b[u + 128]);
    }
    __syncthreads();

    // ---- phase 3: second linears ----
    if (t < 64) {
        float a = (float)ab2[t];
        const bf16* wr = &aw2[t * 128];
        for (int k = 0; k < 128; k += 8) {
            bf16x8 wv = *(const bf16x8*)&wr[k];
#pragma unroll
            for (int q = 0; q < 8; q++) a += bufa[k + q] * (float)wv[q];
        }
        buf2a[t] = gelu_exact(a);
    } else if (t >= 128) {
        const int u = t - 128;
        float a = (float)pb2[u];
        const bf16* wr = &pw2[u * 256];
        for (int k = 0; k < 256; k += 8) {
            bf16x8 wv = *(const bf16x8*)&wr[k];
#pragma unroll
            for (int q = 0; q < 8; q++) a += bufp[k + q] * (float)wv[q];
        }
        buf2p[u] = a;
    }
    __syncthreads();

    // ---- phase 4: LN2 (action W=64 in wave0 || profit W=128), shuffle ----
    {
        float s1 = 0.0f, s2 = 0.0f;
        if (t < 64) {
            const float v = buf2a[t];
            s1 = v; s2 = v * v;
        } else if (t >= 128) {
            const float v = buf2p[t - 128];
            s1 = v; s2 = v * v;
        }
#pragma unroll
        for (int m = 1; m < 64; m <<= 1) {
            s1 += __shfl_xor(s1, m, 64);
            s2 += __shfl_xor(s2, m, 64);
        }
        if (lane == 0) { red[wave * 2] = s1; red[wave * 2 + 1] = s2; }
    }
    __syncthreads();
    if (t < 64) {
        const float S1 = red[0], S2 = red[1];
        const float mean = S1 * (1.0f / 64.0f);
        const float var = fmaxf(S2 * (1.0f / 64.0f) - mean * mean, 0.0f);
        const float inv = rsqrtf(var + 1e-5f);
        buf2a[t] = (buf2a[t] - mean) * inv * (float)aln2s[t] + (float)aln2b[t];
    } else if (t >= 128) {
        const int u = t - 128;
        const float S1 = red[4] + red[6], S2 = red[5] + red[7];
        const float mean = S1 * (1.0f / 128.0f);
        const float var = fmaxf(S2 * (1.0f / 128.0f) - mean * mean, 0.0f);
        const float inv = rsqrtf(var + 1e-5f);
        buf2p[u] = gelu_exact((buf2p[u] - mean) * inv *
                              (float)pln2s[u] + (float)pln2b[u]);
    }
    __syncthreads();

    // ---- phase 5: finals ----
    if (t < 3) {
        float a = (float)ab3[t];
        for (int k = 0; k < 64; k++) a += buf2a[k] * (float)aw3[t * 64 + k];
        out[b * 3 + t] = a;
    }
    {
        float p = 0.0f;
        if (t >= 128) p = buf2p[t - 128] * (float)pw3[t - 128];
#pragma unroll
        for (int m = 1; m < 64; m <<= 1) p += __shfl_xor(p, m, 64);
        if (lane == 0) red[wave] = p;
    }
    __syncthreads();
    if (t == 0) out[48 + b] = (float)pb3[0] + red[2] + red[3];
}

// ---------------------------------------------------------------------------
extern "C" void kernel_launch(void* const* d_in, const int* in_sizes, int n_in,
                              void* d_out, int out_size, void* d_ws, size_t ws_size,
                              hipStream_t stream) {
    char* ws = (char*)d_ws;
    const size_t MB = 1024 * 1024;
    bf16*  h     = (bf16*)(ws);                        // 8193x256
    bf16*  moe0  = (bf16*)(ws + 8 * MB);               // 8193x256
    bf16*  moe1  = (bf16*)(ws + 13 * MB);              // 8193x256
    char*  ctrl  = ws + 20 * MB;
    float* auxs   = (float*)(ctrl + 0);                // 48 f32
    int*   flag   = (int*)(ctrl + 192);
    int*   ntiles = (int*)(ctrl + 256);                // [2]
    int*   tileex = (int*)(ctrl + 320);                // [2][160] = 1280B
    int*   tilebs = (int*)(ctrl + 1664);               // [2][160]
    float* ostage = (float*)(ctrl + 3072);             // 65 f32
    int*   gcnt   = (int*)(ctrl + 3584);               // [16]
    int*   list   = (int*)(ctrl + 4096);               // [2][8][8192] = 512KB
    float* lw     = (float*)(ctrl + 4096 + 524288);    // [2][8][8192] = 512KB
    bf16*  qkv   = (bf16*)(ws + 24 * MB);              // 8192x768
    bf16*  aoutb = (bf16*)(ws + 40 * MB);              // 8192x256
    bf16*  hid0  = (bf16*)(ws + 56 * MB);              // 9216x1024
    bf16*  hid1  = (bf16*)(ws + 80 * MB);              // 9216x1024
    bf16*  vT    = (bf16*)(ws + 104 * MB);             // [16][8][32][512]
    float* pattn = (float*)(ws + 110 * MB);            // 16x256 f32
    bf16*  cvbase = (bf16*)(ws + 112 * MB);            // ~10.6 MB

    InTab tab;
    unsigned off = 0;
    bf16* cv[NIN];
    for (int i = 0; i < NIN; i++) {
        tab.src[i] = d_in[i];
        tab.off[i] = off;
        tab.n[i] = (unsigned)in_sizes[i];
        cv[i] = cvbase + off;
        off += ((unsigned)in_sizes[i] + 1023u) & ~1023u;
    }
    const int cv_blocks = (int)(off >> 10);

    const bf16 *x = cv[0], *in_w = cv[1], *in_b = cv[2], *qkv_w = cv[3], *qkv_b = cv[4],
               *out_w = cv[5], *out_b = cv[6], *gate_w = cv[7], *gate_b = cv[8],
               *e_w1 = cv[9], *e_b1 = cv[10], *e_w2 = cv[11], *e_b2 = cv[12],
               *ln1_s = cv[13], *ln1_b = cv[14], *ln2_s = cv[15], *ln2_b = cv[16],
               *pqkv_w = cv[17], *pqkv_b = cv[18], *pout_w = cv[19], *pout_b = cv[20],
               *a_w1 = cv[21], *a_b1 = cv[22], *a_ln1s = cv[23], *a_ln1b = cv[24],
               *a_w2 = cv[25], *a_b2 = cv[26], *a_ln2s = cv[27], *a_ln2b = cv[28],
               *a_w3 = cv[29], *a_b3 = cv[30],
               *pr_w1 = cv[31], *pr_b1 = cv[32], *pr_ln1s = cv[33], *pr_ln1b = cv[34],
               *pr_w2 = cv[35], *pr_b2 = cv[36], *pr_ln2s = cv[37], *pr_ln2b = cv[38],
               *pr_w3 = cv[39], *pr_b3 = cv[40];

    sniff_kernel<<<1, 256, 0, stream>>>((const unsigned*)d_in[0], flag);
    convert_kernel<<<cv_blocks, 256, 0, stream>>>(tab, cvbase, flag);

    hipMemsetAsync(auxs, 0, 192, stream);
    hipMemsetAsync(gcnt, 0, 64, stream);
    // zero the padding-token row h[8192] (read via list for padded slots)
    hipMemsetAsync((char*)h + (size_t)8192 * 512, 0, 512, stream);
    input_proj_kernel<<<8192, 256, 0, stream>>>(x, in_w, in_b, h);

    for (int l = 0; l < 6; l++) {
        gemm_bt<64, 128, 32, 64, true><<<dim3(128, 6), 256, 0, stream>>>(
            h, qkv_w, qkv_b, qkv, 8192, 768, 256, vT, 0);
        attn_kernel<<<dim3(16, 128), 256, 0, stream>>>(qkv, vT, aoutb);
        proj_gate_ln_kernel<<<512, 256, 0, stream>>>(
            aoutb, out_w, out_b, h, ln1_s, ln1_b, gate_w, gate_b,
            gcnt, list, lw, auxs + l * 8);
        route_build_kernel<<<1, 256, 0, stream>>>(
            gcnt, ntiles, tileex, tilebs, list, lw);
        gemm_moe_w1<<<dim3(288, 8), 256, 0, stream>>>(
            h, e_w1, e_b1, hid0, hid1, list, tileex, tilebs, ntiles);
        gemm_moe_w2<<<dim3(288, 4), 256, 0, stream>>>(
            hid0, hid1, e_w2, e_b2, moe0, moe1, list, lw, tileex, tilebs, ntiles);
        ln_kernel<<<1024, 256, 0, stream>>>(h, moe0, moe1, ln2_s, ln2_b, gcnt);
    }

    // final projection: K+V only (cols 256..767); Q computed in pooled_attn
    gemm_bt<64, 128, 32, 64, true><<<dim3(128, 4), 256, 0, stream>>>(
        h, pqkv_w, pqkv_b, qkv, 8192, 768, 256, vT, 256);
    pooled_attn_kernel<<<128, 256, 0, stream>>>(qkv, vT, h, pqkv_w, pqkv_b, pattn);
    heads_kernel<<<16, 256, 0, stream>>>(
        pattn, pout_w, pout_b,
        a_w1, a_b1, a_ln1s, a_ln1b, a_w2, a_b2, a_ln2s, a_ln2b, a_w3, a_b3,
        pr_w1, pr_b1, pr_ln1s, pr_ln1b, pr_w2, pr_b2, pr_ln2s, pr_ln2b, pr_w3, pr_b3,
        ostage);
    out_convert_kernel<<<1, 128, 0, stream>>>(ostage, auxs, d_out, flag);
}

// Round 17
// 939.309 us; speedup vs baseline: 1.0403x; 1.0403x over previous
//
#include <hip/hip_runtime.h>
#include <hip/hip_bf16.h>
#include <math.h>

// ---------------------------------------------------------------------------
// MoE trading transformer forward, MI355X/gfx950.
// B=16 S=512 F_IN=46 D=256 H=8 (dh=32) L=6 E=8 DFF=1024 OUT=3.
// R24: base = R22 (948.98us best; R23's direct-compaction regressed and is
// reverted). pgl profiling showed it latency-structure-bound (43.5us at 2
// blk/CU vs 45.2 at 1 blk/CU; all pipes <7%): the fused BM=16xBN=256 GEMM
// re-stages the whole 128KB weight per block through ~18 serial phases.
// Split: out-proj via gemm_bt<32,64> (grid 1024, 4/CU, 12KB LDS) into
// projtmp, then ln_gate (grid 512): x=proj+h_old in regs, LN via 16-lane
// shuffle groups, gate/top-2/g_hist tail verbatim from R22's verified pgl.
// scatter_route / w1 / w2 / ln byte-identical to R22.
// ---------------------------------------------------------------------------

typedef __bf16 bf16;
typedef __bf16 bf16x8 __attribute__((ext_vector_type(8)));
typedef __bf16 bf16x4 __attribute__((ext_vector_type(4)));
typedef float f32x4 __attribute__((ext_vector_type(4)));

#define NIN 41

#define GLOAD_LDS(g, l)                                                    \
    __builtin_amdgcn_global_load_lds(                                      \
        (const __attribute__((address_space(1))) void*)(g),                \
        (__attribute__((address_space(3))) void*)(l), 16, 0, 0)

struct InTab {
    const void* src[NIN];
    unsigned off[NIN];
    unsigned n[NIN];
};

__device__ __forceinline__ float gelu_exact(float x) {
    return 0.5f * x * (1.0f + erff(x * 0.70710678118654752f));
}

// exact-GELU via Abramowitz-Stegun 7.1.26 erf (|err| < 1.5e-7).
__device__ __forceinline__ float gelu_fast(float x) {
    const float u = fabsf(x) * 0.70710678118654752f;
    const float t = 1.0f / (1.0f + 0.3275911f * u);
    const float p = t * (0.254829592f + t * (-0.284496736f + t * (1.421413741f +
                    t * (-1.453152027f + t * 1.061405429f))));
    const float er = 1.0f - p * __builtin_exp2f(-u * u * 1.4426950408889634f);
    const float s = (x >= 0.0f) ? er : -er;
    return 0.5f * x * (1.0f + s);
}

// ---------------------------------------------------------------------------
// Dtype sniffer (f32 vs bf16 storage). flag: 1=bf16, 0=f32.
// ---------------------------------------------------------------------------
__global__ void sniff_kernel(const unsigned* __restrict__ xw, int* __restrict__ flag) {
    __shared__ int cnt;
    if (threadIdx.x == 0) cnt = 0;
    __syncthreads();
    const unsigned w = xw[threadIdx.x];
    const unsigned ex = (w >> 7) & 0xFFu;
    if (ex >= 107u && ex <= 133u) atomicAdd(&cnt, 1);
    __syncthreads();
    if (threadIdx.x == 0) *flag = (cnt >= 192) ? 1 : 0;
}

__global__ __launch_bounds__(256) void convert_kernel(
    InTab tab, bf16* __restrict__ dst_base, const int* __restrict__ flag) {
    const unsigned g0 = blockIdx.x * 1024u;
    int inp = 0;
#pragma unroll
    for (int i = 1; i < NIN; i++)
        if (g0 >= tab.off[i]) inp = i;
    const unsigned n = tab.n[inp];
    const unsigned i0 = g0 - tab.off[inp] + threadIdx.x * 4u;
    if (i0 >= n) return;
    const int isbf = *flag;
    bf16* dst = dst_base + tab.off[inp];
    const unsigned end = (i0 + 4u > n) ? n : i0 + 4u;
    if (isbf) {
        const unsigned short* s = (const unsigned short*)tab.src[inp];
        for (unsigned i = i0; i < end; i++) ((unsigned short*)dst)[i] = s[i];
    } else {
        const float* s = (const float*)tab.src[inp];
        for (unsigned i = i0; i < end; i++) dst[i] = (bf16)s[i];
    }
}

// aux folded in here (reads the 48 per-layer/expert softmax sums directly).
__global__ void out_convert_kernel(const float* __restrict__ st,
                                   const float* __restrict__ auxsums,
                                   void* __restrict__ out,
                                   const int* __restrict__ flag) {
    const int i = threadIdx.x;
    if (i >= 65) return;
    float v;
    if (i == 64) {
        float tot = 0.0f;
        for (int l = 0; l < 6; l++)
            for (int e = 0; e < 8; e++) {
                const float mn = auxsums[l * 8 + e] * (1.0f / 8192.0f);
                tot += 8.0f * mn * mn;
            }
        v = tot;
    } else {
        v = st[i];
    }
    if (*flag) ((bf16*)out)[i] = (bf16)v;
    else       ((float*)out)[i] = v;
}

// swizzled LDS element index for (tile-local row r, col-chunk c) [chunks of 8 bf16]
#define SWZ(r, c) (((r) * 8 + ((c) ^ ((r) & 7))) * 8)

// ---------------------------------------------------------------------------
// Dense MFMA GEMM, async-staged + swizzled:  C = A @ W'^T + bias', where
// W'/bias'/C columns start at global column ncol_off. VTOUT: global cols
// >= 512 go transposed to vT[b][h][d][s] (bf16x4 stores).
// ---------------------------------------------------------------------------
template <int BM, int BN, int WM, int WN, bool VTOUT>
__global__ __launch_bounds__(256) void gemm_bt(
    const bf16* __restrict__ A, const bf16* __restrict__ W,
    const bf16* __restrict__ bias, bf16* __restrict__ C,
    int M, int N, int K, bf16* __restrict__ vT, int ncol_off) {
    constexpr int BK = 64;
    __shared__ alignas(16) bf16 smem[BM * BK + BN * BK];
    bf16* As = smem;
    bf16* Ws = smem + BM * BK;
    const int bm0 = blockIdx.x * BM;
    const int bn0g = blockIdx.y * BN + ncol_off;      // global column base
    const int tid = threadIdx.x;
    const int wave = tid >> 6, lane = tid & 63;
    constexpr int WCOLS = BN / WN;
    const int wm0 = (wave / WCOLS) * WM, wn0 = (wave % WCOLS) * WN;
    constexpr int MT = WM / 16, NT = WN / 16;
    f32x4 acc[MT][NT] = {};
    const int frow = lane & 15, fquad = lane >> 4;

    constexpr int AIT = BM / 32, BIT = BN / 32;
    const bf16* ag[AIT];
    const bf16* bg[BIT];
    unsigned al[AIT], bl[BIT];
#pragma unroll
    for (int i = 0; i < AIT; i++) {
        const int d = wave * (BM * 2) + i * 64 + lane;
        const int r = d >> 3, c = ((d & 7) ^ (r & 7)) * 8;
        ag[i] = A + (size_t)(bm0 + r) * K + c;
        al[i] = (unsigned)(wave * (BM * 2) + i * 64) * 8u;
    }
#pragma unroll
    for (int i = 0; i < BIT; i++) {
        const int d = wave * (BN * 2) + i * 64 + lane;
        const int r = d >> 3, c = ((d & 7) ^ (r & 7)) * 8;
        bg[i] = W + (size_t)(bn0g + r) * K + c;
        bl[i] = (unsigned)(wave * (BN * 2) + i * 64) * 8u;
    }

    for (int k0 = 0; k0 < K; k0 += BK) {
#pragma unroll
        for (int i = 0; i < AIT; i++) GLOAD_LDS(ag[i] + k0, &As[al[i]]);
#pragma unroll
        for (int i = 0; i < BIT; i++) GLOAD_LDS(bg[i] + k0, &Ws[bl[i]]);
        __syncthreads();
#pragma unroll
        for (int ks = 0; ks < BK / 32; ks++) {
            bf16x8 af[MT], bfr[NT];
#pragma unroll
            for (int mt = 0; mt < MT; mt++) {
                const int r = wm0 + mt * 16 + frow;
                af[mt] = *(const bf16x8*)&As[SWZ(r, ks * 4 + fquad)];
            }
#pragma unroll
            for (int nt = 0; nt < NT; nt++) {
                const int r = wn0 + nt * 16 + frow;
                bfr[nt] = *(const bf16x8*)&Ws[SWZ(r, ks * 4 + fquad)];
            }
#pragma unroll
            for (int mt = 0; mt < MT; mt++)
#pragma unroll
                for (int nt = 0; nt < NT; nt++)
                    acc[mt][nt] = __builtin_amdgcn_mfma_f32_16x16x32_bf16(
                        af[mt], bfr[nt], acc[mt][nt], 0, 0, 0);
        }
        __syncthreads();
    }

    if (VTOUT && bn0g >= 512) {
        // V path: 4 consecutive s per lane -> one bf16x4 store.
#pragma unroll
        for (int mt = 0; mt < MT; mt++)
#pragma unroll
            for (int nt = 0; nt < NT; nt++) {
                const int gn = bn0g + wn0 + nt * 16 + frow;
                const float bv = (float)bias[gn];
                bf16x4 o4;
#pragma unroll
                for (int r = 0; r < 4; r++) o4[r] = (bf16)(acc[mt][nt][r] + bv);
                const int gm0 = bm0 + wm0 + mt * 16 + fquad * 4;
                const int d = gn - 512;
                *(bf16x4*)&vT[((size_t)((gm0 >> 9) * 8 + (d >> 5)) * 32 + (d & 31)) * 512 +
                              (gm0 & 511)] = o4;
            }
    } else {
        // C path: stage tile in LDS (reuse smem), then coalesced bf16x8 stores.
        bf16* Cs = smem;
#pragma unroll
        for (int mt = 0; mt < MT; mt++)
#pragma unroll
            for (int nt = 0; nt < NT; nt++) {
                const int cl = wn0 + nt * 16 + frow;
                const float bv = (float)bias[bn0g + cl];
#pragma unroll
                for (int r = 0; r < 4; r++)
                    Cs[(wm0 + mt * 16 + fquad * 4 + r) * BN + cl] =
                        (bf16)(acc[mt][nt][r] + bv);
            }
        __syncthreads();
        constexpr int CPR = BN / 8;                       // chunks per row
        constexpr int CH = (BM * BN) / (256 * 8);         // chunks per thread
#pragma unroll
        for (int i = 0; i < CH; i++) {
            const int ch = tid + i * 256;
            const int row = ch / CPR;
            const int col = (ch % CPR) * 8;
            *(bf16x8*)&C[(size_t)(bm0 + row) * N + bn0g + col] =
                *(const bf16x8*)&Cs[row * BN + col];
        }
    }
}

// ---------------------------------------------------------------------------
// MoE w1 (both slots, one launch): hid{slot}[i] = GELU(h[list[i]] @ w1_e^T + b1_e)
// BM=64, BN=128 -> grid (288, 8) = 2304 blocks for TLP. LDS 24 KB.
// ---------------------------------------------------------------------------
__global__ __launch_bounds__(256) void gemm_moe_w1(
    const bf16* __restrict__ A, const bf16* __restrict__ Wb,
    const bf16* __restrict__ biasb, bf16* __restrict__ hid0,
    bf16* __restrict__ hid1, const int* __restrict__ list,
    const int* __restrict__ tile_ex, const int* __restrict__ ntiles) {
    constexpr int BM = 64, BN = 128, BK = 64;
    constexpr int N = 1024, K = 256;
    const int slot = (blockIdx.x >= 144) ? 1 : 0;
    const int xi = (int)blockIdx.x - slot * 144;
    if (xi >= (ntiles[slot] << 1)) return;
    __shared__ alignas(16) bf16 smem[BM * BK + BN * BK];   // 24 KB
    bf16* As = smem;
    bf16* Ws = smem + BM * BK;
    const int* mylist = list + slot * 9216;
    const int e = tile_ex[slot * 72 + (xi >> 1)];
    const bf16* W = Wb + (size_t)e * N * K;
    const bf16* bias = biasb + e * N;
    bf16* C = slot ? hid1 : hid0;
    const int bm0 = xi * BM, bn0 = blockIdx.y * BN;
    const int tid = threadIdx.x;
    const int wave = tid >> 6, lane = tid & 63;
    const int wm0 = (wave >> 1) * 32, wn0 = (wave & 1) * 64;  // 2x2, 32x64/wave
    constexpr int MT = 2, NT = 4;
    f32x4 acc[MT][NT] = {};
    const int frow = lane & 15, fquad = lane >> 4;

    const bf16* ag[2];
    const bf16* bg[4];
    unsigned al[2], bl[4];
#pragma unroll
    for (int i = 0; i < 2; i++) {
        const int d = wave * 128 + i * 64 + lane;
        const int r = d >> 3, c = ((d & 7) ^ (r & 7)) * 8;
        ag[i] = A + (size_t)mylist[bm0 + r] * K + c;
        al[i] = (unsigned)(wave * 128 + i * 64) * 8u;
    }
#pragma unroll
    for (int i = 0; i < 4; i++) {
        const int d = wave * 256 + i * 64 + lane;
        const int r = d >> 3, c = ((d & 7) ^ (r & 7)) * 8;
        bg[i] = W + (size_t)(bn0 + r) * K + c;
        bl[i] = (unsigned)(wave * 256 + i * 64) * 8u;
    }

    for (int k0 = 0; k0 < K; k0 += BK) {
#pragma unroll
        for (int i = 0; i < 2; i++) GLOAD_LDS(ag[i] + k0, &As[al[i]]);
#pragma unroll
        for (int i = 0; i < 4; i++) GLOAD_LDS(bg[i] + k0, &Ws[bl[i]]);
        __syncthreads();
#pragma unroll
        for (int ks = 0; ks < 2; ks++) {
            bf16x8 af[MT], bfr[NT];
#pragma unroll
            for (int mt = 0; mt < MT; mt++) {
                const int r = wm0 + mt * 16 + frow;
                af[mt] = *(const bf16x8*)&As[SWZ(r, ks * 4 + fquad)];
            }
#pragma unroll
            for (int nt = 0; nt < NT; nt++) {
                const int r = wn0 + nt * 16 + frow;
                bfr[nt] = *(const bf16x8*)&Ws[SWZ(r, ks * 4 + fquad)];
            }
#pragma unroll
            for (int mt = 0; mt < MT; mt++)
#pragma unroll
                for (int nt = 0; nt < NT; nt++)
                    acc[mt][nt] = __builtin_amdgcn_mfma_f32_16x16x32_bf16(
                        af[mt], bfr[nt], acc[mt][nt], 0, 0, 0);
        }
        __syncthreads();
    }

    // epilogue: GELU -> LDS tile (64x128, 16 KB fits in smem) -> coalesced
    {
        bf16* Cs = smem;
#pragma unroll
        for (int mt = 0; mt < MT; mt++)
#pragma unroll
            for (int nt = 0; nt < NT; nt++) {
                const int cl = wn0 + nt * 16 + frow;
                const float bv = (float)bias[bn0 + cl];
#pragma unroll
                for (int r = 0; r < 4; r++)
                    Cs[(wm0 + mt * 16 + fquad * 4 + r) * BN + cl] =
                        (bf16)gelu_fast(acc[mt][nt][r] + bv);
            }
        __syncthreads();
#pragma unroll
        for (int i = 0; i < 4; i++) {
            const int ch = tid + i * 256;
            const int row = ch >> 4;            // 16 chunks per 128-col row
            const int col = (ch & 15) * 8;
            *(bf16x8*)&C[(size_t)(bm0 + row) * N + bn0 + col] =
                *(const bf16x8*)&Cs[row * BN + col];
        }
    }
}

// ---------------------------------------------------------------------------
// MoE w2, both slots in one launch (disjoint outputs moe0/moe1):
// moe{slot}[list[i]] = lw[i]*(hid{slot}[i] @ w2_e^T + b2_e)
// BM=64, BN=64, BK=64 -> grid (288, 4) = 1152 blocks. LDS 16 KB. 16-row waves.
// ---------------------------------------------------------------------------
__global__ __launch_bounds__(256) void gemm_moe_w2(
    const bf16* __restrict__ hid0, const bf16* __restrict__ hid1,
    const bf16* __restrict__ Wb, const bf16* __restrict__ biasb,
    bf16* __restrict__ moe0, bf16* __restrict__ moe1,
    const int* __restrict__ list, const float* __restrict__ lw,
    const int* __restrict__ tile_ex, const int* __restrict__ ntiles) {
    constexpr int BM = 64, BN = 64, BK = 64;
    constexpr int N = 256, K = 1024;
    const int slot = (blockIdx.x >= 144) ? 1 : 0;
    const int xi = (int)blockIdx.x - slot * 144;
    if (xi >= (ntiles[slot] << 1)) return;
    __shared__ alignas(16) bf16 smem[BM * BK + BN * BK];   // 16 KB
    bf16* As = smem;
    bf16* Ws = smem + BM * BK;
    const bf16* A = slot ? hid1 : hid0;
    bf16* C = slot ? moe1 : moe0;
    const int* mylist = list + slot * 9216;
    const float* mylw = lw + slot * 9216;
    const int e = tile_ex[slot * 72 + (xi >> 1)];
    const bf16* W = Wb + (size_t)e * N * K;
    const bf16* bias = biasb + e * N;
    const int bm0 = xi * BM, bn0 = blockIdx.y * BN;
    const int tid = threadIdx.x;
    const int wave = tid >> 6, lane = tid & 63;
    const int wm0 = wave * 16;                 // 4 waves, 16x64 each
    constexpr int NT = 4;
    f32x4 acc[NT] = {};
    const int frow = lane & 15, fquad = lane >> 4;

    const bf16* ag[2];
    const bf16* bg[2];
    unsigned al[2], bl[2];
#pragma unroll
    for (int i = 0; i < 2; i++) {
        const int d = wave * 128 + i * 64 + lane;
        const int r = d >> 3, c = ((d & 7) ^ (r & 7)) * 8;
        ag[i] = A + (size_t)(bm0 + r) * K + c;
        al[i] = (unsigned)(wave * 128 + i * 64) * 8u;
        bg[i] = W + (size_t)(bn0 + r) * K + c;
        bl[i] = al[i];
    }

    for (int k0 = 0; k0 < K; k0 += BK) {
#pragma unroll
        for (int i = 0; i < 2; i++) GLOAD_LDS(ag[i] + k0, &As[al[i]]);
#pragma unroll
        for (int i = 0; i < 2; i++) GLOAD_LDS(bg[i] + k0, &Ws[bl[i]]);
        __syncthreads();
#pragma unroll
        for (int ks = 0; ks < 2; ks++) {
            bf16x8 af, bfr[NT];
            af = *(const bf16x8*)&As[SWZ(wm0 + frow, ks * 4 + fquad)];
#pragma unroll
            for (int nt = 0; nt < NT; nt++) {
                const int r = nt * 16 + frow;
                bfr[nt] = *(const bf16x8*)&Ws[SWZ(r, ks * 4 + fquad)];
            }
#pragma unroll
            for (int nt = 0; nt < NT; nt++)
                acc[nt] = __builtin_amdgcn_mfma_f32_16x16x32_bf16(
                    af, bfr[nt], acc[nt], 0, 0, 0);
        }
        __syncthreads();
    }

    // epilogue: bias+lw -> LDS tile (64x64, 8 KB) -> coalesced scattered-row
    {
        bf16* Cs = smem;
        float lwv[4];
#pragma unroll
        for (int r = 0; r < 4; r++)
            lwv[r] = mylw[bm0 + wm0 + fquad * 4 + r];
#pragma unroll
        for (int nt = 0; nt < NT; nt++) {
            const int cl = nt * 16 + frow;
            const float bv = (float)bias[bn0 + cl];
#pragma unroll
            for (int r = 0; r < 4; r++)
                Cs[(wm0 + fquad * 4 + r) * BN + cl] =
                    (bf16)(lwv[r] * (acc[nt][r] + bv));
        }
        __syncthreads();
#pragma unroll
        for (int i = 0; i < 2; i++) {
            const int ch = tid + i * 256;
            const int row = ch >> 3;            // 8 chunks per 64-col row
            const int col = (ch & 7) * 8;
            *(bf16x8*)&C[(size_t)mylist[bm0 + row] * 256 + bn0 + col] =
                *(const bf16x8*)&Cs[row * BN + col];
        }
    }
}

// ---------------------------------------------------------------------------
// Input projection + positional encoding. grid 8192, block 256.
// ---------------------------------------------------------------------------
__global__ __launch_bounds__(256) void input_proj_kernel(
    const bf16* __restrict__ x, const bf16* __restrict__ w,
    const bf16* __restrict__ b, bf16* __restrict__ h) {
    const int m = blockIdx.x, t = threadIdx.x;
    __shared__ float xs[46];
    if (t < 46) xs[t] = (float)x[m * 46 + t];
    __syncthreads();
    float acc = (float)b[t];
#pragma unroll
    for (int k = 0; k < 46; k++) acc += xs[k] * (float)w[t * 46 + k];
    const int s = m & 511;
    const int i = t >> 1;
    const float dv = expf((float)(2 * i) * (-9.210340371976184f / 256.0f));
    const float ang = (float)s * dv;
    const float pe = (t & 1) ? cosf(ang) : sinf(ang);
    h[(size_t)m * 256 + t] = (bf16)(acc + pe);
}

// ---------------------------------------------------------------------------
// ln2: h = LN(h + moe0 + moe1)*s + b. bf16x8 loads, 2 tokens/wave. grid 1024.
// ---------------------------------------------------------------------------
__global__ __launch_bounds__(256) void ln_kernel(
    bf16* __restrict__ h, const bf16* __restrict__ a0,
    const bf16* __restrict__ a1, const bf16* __restrict__ s,
    const bf16* __restrict__ b) {
    const int wv = threadIdx.x >> 6, lane = threadIdx.x & 63;
    const int m = blockIdx.x * 8 + wv * 2 + (lane >> 5);
    const int c0 = (lane & 31) * 8;
    const size_t off = (size_t)m * 256 + c0;
    bf16x8 hv = *(const bf16x8*)&h[off];
    bf16x8 av = *(const bf16x8*)&a0[off];
    bf16x8 bv2 = *(const bf16x8*)&a1[off];
    float x[8];
    float s1 = 0.0f, s2 = 0.0f;
#pragma unroll
    for (int j = 0; j < 8; j++) {
        x[j] = (float)hv[j] + (float)av[j] + (float)bv2[j];
        s1 += x[j];
        s2 += x[j] * x[j];
    }
#pragma unroll
    for (int msk = 1; msk < 32; msk <<= 1) {
        s1 += __shfl_xor(s1, msk, 64);
        s2 += __shfl_xor(s2, msk, 64);
    }
    const float mean = s1 * (1.0f / 256.0f);
    const float var = fmaxf(s2 * (1.0f / 256.0f) - mean * mean, 0.0f);
    const float inv = rsqrtf(var + 1e-5f);
    bf16x8 sv = *(const bf16x8*)&s[c0];
    bf16x8 bv = *(const bf16x8*)&b[c0];
    bf16x8 o;
#pragma unroll
    for (int j = 0; j < 8; j++)
        o[j] = (bf16)((x[j] - mean) * inv * (float)sv[j] + (float)bv[j]);
    *(bf16x8*)&h[off] = o;
}

// ---------------------------------------------------------------------------
// ln_gate: x = projtmp + h_old (bias already in projtmp); LN1 -> h write;
// gate logits + top-2 + per-block histogram + aux softmax sums.
// grid 512 (16 tokens/block). LN via 16-lane shuffle groups (1 row per
// 16-thread group -> no cross-wave reduce, no barrier before gate phase).
// Tail (gate/top2/hist/aux) verbatim from R22's verified proj_gate_ln.
// ---------------------------------------------------------------------------
__global__ __launch_bounds__(256) void ln_gate_kernel(
    const bf16* __restrict__ proj, bf16* __restrict__ h,
    const bf16* __restrict__ lns, const bf16* __restrict__ lnb,
    const bf16* __restrict__ gw, const bf16* __restrict__ gb,
    int* __restrict__ top_e, float* __restrict__ top_w,
    int* __restrict__ g_hist, float* __restrict__ aux_sums) {
    __shared__ alignas(16) bf16 hs[16 * 264];    // LN output, padded stride
    __shared__ alignas(16) bf16 gws[8 * 264];
    __shared__ float lg[128];                    // 16 tokens x 8 experts
    __shared__ int sh_hist[16];
    __shared__ float sh_aux[8];

    const int bm0 = blockIdx.x * 16;
    const int tid = threadIdx.x;
    const int row = tid >> 4, seg = tid & 15;    // 16 threads/row, 16 cols each

    // gate weights stage
    {
        const int e = tid >> 5, k = (tid & 31) * 8;
        *(bf16x8*)&gws[e * 264 + k] = *(const bf16x8*)&gw[e * 256 + k];
    }
    if (tid < 16) sh_hist[tid] = 0;
    if (tid < 8) sh_aux[tid] = 0.0f;

    // ---- x = proj + h_old (16 elems/thread); row sums ----
    const size_t base = (size_t)(bm0 + row) * 256 + seg * 16;
    bf16x8 p0 = *(const bf16x8*)&proj[base];
    bf16x8 p1 = *(const bf16x8*)&proj[base + 8];
    bf16x8 h0 = *(const bf16x8*)&h[base];
    bf16x8 h1 = *(const bf16x8*)&h[base + 8];
    float x[16];
    float s1 = 0.0f, s2 = 0.0f;
#pragma unroll
    for (int j = 0; j < 8; j++) {
        x[j] = (float)p0[j] + (float)h0[j];
        x[8 + j] = (float)p1[j] + (float)h1[j];
        s1 += x[j] + x[8 + j];
        s2 += x[j] * x[j] + x[8 + j] * x[8 + j];
    }
    // reduce within the 16-lane group (bits 0-3 stay in-group)
#pragma unroll
    for (int m = 1; m < 16; m <<= 1) {
        s1 += __shfl_xor(s1, m, 64);
        s2 += __shfl_xor(s2, m, 64);
    }
    const float mean = s1 * (1.0f / 256.0f);
    const float var = fmaxf(s2 * (1.0f / 256.0f) - mean * mean, 0.0f);
    const float inv = rsqrtf(var + 1e-5f);

    // ---- LN output -> h (global) and hs (LDS for gate phase) ----
    {
        bf16x8 sv0 = *(const bf16x8*)&lns[seg * 16];
        bf16x8 sv1 = *(const bf16x8*)&lns[seg * 16 + 8];
        bf16x8 bv0 = *(const bf16x8*)&lnb[seg * 16];
        bf16x8 bv1 = *(const bf16x8*)&lnb[seg * 16 + 8];
        bf16x8 o0, o1;
#pragma unroll
        for (int j = 0; j < 8; j++) {
            o0[j] = (bf16)((x[j] - mean) * inv * (float)sv0[j] + (float)bv0[j]);
            o1[j] = (bf16)((x[8 + j] - mean) * inv * (float)sv1[j] + (float)bv1[j]);
        }
        *(bf16x8*)&h[base] = o0;
        *(bf16x8*)&h[base + 8] = o1;
        bf16* dst = &hs[row * 264 + seg * 16];
        *(bf16x8*)&dst[0] = o0;
        *(bf16x8*)&dst[8] = o1;
    }
    __syncthreads();

    // ---- gate logits (verbatim R22) ----
    if (tid < 128) {
        const int r8 = tid >> 3, e = tid & 7;
        float acg = (float)gb[e];
        for (int k = 0; k < 256; k += 8) {
            bf16x8 hv = *(const bf16x8*)&hs[r8 * 264 + k];
            bf16x8 wv = *(const bf16x8*)&gws[e * 264 + k];
#pragma unroll
            for (int q = 0; q < 8; q++) acg += (float)hv[q] * (float)wv[q];
        }
        lg[r8 * 8 + e] = acg;
    }
    __syncthreads();

    // ---- top-2 + aux per token (verbatim R22) ----
    if (tid < 16) {
        const int tok = bm0 + tid;
        float l[8];
#pragma unroll
        for (int j = 0; j < 8; j++) l[j] = lg[tid * 8 + j];
        int i0 = 0;
#pragma unroll
        for (int j = 1; j < 8; j++)
            if (l[j] > l[i0]) i0 = j;
        int i1 = -1;
#pragma unroll
        for (int j = 0; j < 8; j++)
            if (j != i0 && (i1 < 0 || l[j] > l[i1])) i1 = j;
        const float p0w = 1.0f / (1.0f + expf(l[i1] - l[i0]));
        top_e[tok] = i0;         top_w[tok] = p0w;
        top_e[8192 + tok] = i1;  top_w[8192 + tok] = 1.0f - p0w;
        atomicAdd(&sh_hist[i0], 1);
        atomicAdd(&sh_hist[8 + i1], 1);
        const float mx = l[i0];
        float se = 0.0f;
#pragma unroll
        for (int j = 0; j < 8; j++) { l[j] = expf(l[j] - mx); se += l[j]; }
        const float si = 1.0f / se;
#pragma unroll
        for (int j = 0; j < 8; j++) atomicAdd(&sh_aux[j], l[j] * si);
    }
    __syncthreads();
    if (tid < 16) g_hist[blockIdx.x * 16 + tid] = sh_hist[tid];
    if (tid < 8) atomicAdd(&aux_sums[tid], sh_aux[tid]);
}

// ---------------------------------------------------------------------------
// Merged route-build + scatter. grid 64 x 256. g_hist is [512][16]
// (one histogram per ln_gate block of 16 tokens). Verbatim R22.
// ---------------------------------------------------------------------------
__global__ __launch_bounds__(256) void scatter_route_kernel(
    const int* __restrict__ g_hist, const int* __restrict__ top_e,
    const float* __restrict__ top_w, int* __restrict__ ntiles,
    int* __restrict__ tile_ex, int* __restrict__ list, float* __restrict__ lw) {
    __shared__ int gh[512][16];                  // 32 KB
    __shared__ int ps[16][8];
    __shared__ int s_cnt[16], s_pre[16], s_off[16], pos[16];
    const int tid = threadIdx.x;
    for (int i = tid; i < 8192; i += 256) gh[i >> 4][i & 15] = g_hist[i];
    __syncthreads();
    if (tid < 128) {
        const int se = tid >> 3, ch = tid & 7;
        int s = 0;
        for (int b = ch * 64; b < ch * 64 + 64; b++) s += gh[b][se];
        ps[se][ch] = s;
    }
    __syncthreads();
    if (tid < 16) {
        int run = 0;
        for (int ch = 0; ch < 8; ch++) run += ps[tid][ch];
        const int b0 = (int)blockIdx.x * 8;  // 16-token blocks before this one
        int pre = 0;
        for (int ch = 0; ch < (b0 >> 6); ch++) pre += ps[tid][ch];
        for (int b = b0 & ~63; b < b0; b++) pre += gh[b][tid];
        s_cnt[tid] = run;
        s_pre[tid] = pre;
    }
    __syncthreads();
    if (tid < 2) {
        const int slot = tid;
        int o = 0;
        for (int e2 = 0; e2 < 8; e2++) {
            s_off[slot * 8 + e2] = o;
            const int nt = (s_cnt[slot * 8 + e2] + 127) >> 7;
            if (blockIdx.x == 0)
                for (int t = 0; t < nt; t++) tile_ex[slot * 72 + (o >> 7) + t] = e2;
            o += nt << 7;
        }
        if (blockIdx.x == 0) ntiles[slot] = o >> 7;
    }
    __syncthreads();
    if (tid < 16) pos[tid] = s_off[tid] + s_pre[tid];
    __syncthreads();
    if (blockIdx.x == 0) {
        for (int idx = tid; idx < 16 * 128; idx += 256) {
            const int seg = idx >> 7, i = idx & 127;
            const int slot = seg >> 3;
            const int start = s_off[seg] + s_cnt[seg];
            const int end = s_off[seg] + ((s_cnt[seg] + 127) & ~127);
            const int p = start + i;
            if (p < end) {
                list[slot * 9216 + p] = 8192;
                lw[slot * 9216 + p] = 0.0f;
            }
        }
    }
    if (tid < 128) {
        const int tok = blockIdx.x * 128 + tid;
#pragma unroll
        for (int slot = 0; slot < 2; slot++) {
            const int e = top_e[slot * 8192 + tok];
            const float w = top_w[slot * 8192 + tok];
            const int idx = atomicAdd(&pos[slot * 8 + e], 1);
            list[slot * 9216 + idx] = tok;
            lw[slot * 9216 + idx] = w;
        }
    }
}

// ---------------------------------------------------------------------------
// Fused attention, one (b,h) x 32-query tile per block. grid (16,128).
// ---------------------------------------------------------------------------
__global__ __launch_bounds__(256) void attn_kernel(
    const bf16* __restrict__ qkv, const bf16* __restrict__ vT,
    bf16* __restrict__ aout) {
    __shared__ alignas(16) bf16 P[32][520];
    __shared__ float wsum[4][32];
    __shared__ float sinv[32];
    const int s0 = blockIdx.x * 32;
    const int b = blockIdx.y >> 3, hh = blockIdx.y & 7;
    const int tid = threadIdx.x, wave = tid >> 6, lane = tid & 63;
    const int frow = lane & 15, fquad = lane >> 4;
    const size_t base = (size_t)b * 512;
    const float CST = 0.25505654f;  // (1/sqrt(32)) * log2(e)

    bf16x8 qf[2];
#pragma unroll
    for (int mt = 0; mt < 2; mt++)
        qf[mt] = *(const bf16x8*)&qkv[(base + s0 + mt * 16 + frow) * 768 + hh * 32 + fquad * 8];
    float rsum[2][4] = {};
#pragma unroll
    for (int k8 = 0; k8 < 8; k8++) {
        const int key0 = (wave * 8 + k8) * 16;
        bf16x8 kf = *(const bf16x8*)&qkv[(base + key0 + frow) * 768 + 256 + hh * 32 + fquad * 8];
#pragma unroll
        for (int mt = 0; mt < 2; mt++) {
            f32x4 c = {};
            c = __builtin_amdgcn_mfma_f32_16x16x32_bf16(qf[mt], kf, c, 0, 0, 0);
#pragma unroll
            for (int r = 0; r < 4; r++) {
                const float e_ = __builtin_exp2f(fminf(c[r] * CST, 60.0f));
                P[mt * 16 + fquad * 4 + r][key0 + frow] = (bf16)e_;
                rsum[mt][r] += e_;
            }
        }
    }
#pragma unroll
    for (int mt = 0; mt < 2; mt++)
#pragma unroll
        for (int r = 0; r < 4; r++) {
#pragma unroll
            for (int m = 1; m < 16; m <<= 1)
                rsum[mt][r] += __shfl_xor(rsum[mt][r], m, 64);
        }
    if (frow == 0) {
#pragma unroll
        for (int mt = 0; mt < 2; mt++)
#pragma unroll
            for (int r = 0; r < 4; r++)
                wsum[wave][mt * 16 + fquad * 4 + r] = rsum[mt][r];
    }
    __syncthreads();
    if (tid < 32)
        sinv[tid] = 1.0f / (wsum[0][tid] + wsum[1][tid] + wsum[2][tid] + wsum[3][tid]);

    {
        const int mt = wave >> 1, nt = wave & 1;
        const bf16* vrow = &vT[((size_t)(b * 8 + hh) * 32 + nt * 16 + frow) * 512];
        f32x4 o = {};
#pragma unroll
        for (int ks = 0; ks < 16; ks++) {
            bf16x8 pf = *(const bf16x8*)&P[mt * 16 + frow][ks * 32 + fquad * 8];
            bf16x8 vf = *(const bf16x8*)&vrow[ks * 32 + fquad * 8];
            o = __builtin_amdgcn_mfma_f32_16x16x32_bf16(pf, vf, o, 0, 0, 0);
        }
        __syncthreads();
        const int r0 = mt * 16 + fquad * 4;
#pragma unroll
        for (int r = 0; r < 4; r++)
            aout[(base + s0 + r0 + r) * 256 + hh * 32 + nt * 16 + frow] =
                (bf16)(o[r] * sinv[r0 + r]);
    }
}

// ---------------------------------------------------------------------------
// Pooled attention: one block per (b,h). Computes its own q (16 last-token
// rows; the final qkv GEMM no longer produces Q). 4 waves split 512 keys;
// f32 softmax; output pattn f32 (16x256).
// ---------------------------------------------------------------------------
__global__ __launch_bounds__(256) void pooled_attn_kernel(
    const bf16* __restrict__ qkv, const bf16* __restrict__ vT,
    const bf16* __restrict__ hsrc, const bf16* __restrict__ wq,
    const bf16* __restrict__ qb, float* __restrict__ pattn) {
    __shared__ float p_lds[512];
    __shared__ float qs[32];
    __shared__ float wmax[4], wsum[4];
    const int b = blockIdx.x >> 3, hh = blockIdx.x & 7;
    const int tid = threadIdx.x, wave = tid >> 6, lane = tid & 63;
    const size_t base = (size_t)b * 512;
    const float scale = 0.17677669529663687f;

    // ---- q = h[last token] @ wq^T + bq, 8 threads per dim ----
    {
        const int d = tid >> 3, seg = tid & 7;
        const bf16* hr = &hsrc[(base + 511) * 256 + seg * 32];
        const bf16* wr = &wq[(size_t)(hh * 32 + d) * 256 + seg * 32];
        float a = 0.0f;
#pragma unroll
        for (int k = 0; k < 32; k += 8) {
            bf16x8 hv = *(const bf16x8*)&hr[k];
            bf16x8 wv = *(const bf16x8*)&wr[k];
#pragma unroll
            for (int q = 0; q < 8; q++) a += (float)hv[q] * (float)wv[q];
        }
#pragma unroll
        for (int m = 1; m < 8; m <<= 1) a += __shfl_xor(a, m, 64);
        if (seg == 0) qs[d] = a + (float)qb[hh * 32 + d];
    }
    __syncthreads();

    float s[2];
    float mx = -1e30f;
#pragma unroll
    for (int j = 0; j < 2; j++) {
        const int key = wave * 128 + j * 64 + lane;
        const bf16* kr = &qkv[(base + key) * 768 + 256 + hh * 32];
        float acc = 0.0f;
#pragma unroll
        for (int i = 0; i < 4; i++) {
            bf16x8 kv = *(const bf16x8*)&kr[i * 8];
#pragma unroll
            for (int q = 0; q < 8; q++) acc += qs[i * 8 + q] * (float)kv[q];
        }
        s[j] = acc * scale;
        mx = fmaxf(mx, s[j]);
    }
#pragma unroll
    for (int m = 1; m < 64; m <<= 1) mx = fmaxf(mx, __shfl_xor(mx, m, 64));
    if (lane == 0) wmax[wave] = mx;
    __syncthreads();
    const float bmx = fmaxf(fmaxf(wmax[0], wmax[1]), fmaxf(wmax[2], wmax[3]));
    float se = 0.0f;
#pragma unroll
    for (int j = 0; j < 2; j++) {
        s[j] = expf(s[j] - bmx);
        se += s[j];
        p_lds[wave * 128 + j * 64 + lane] = s[j];
    }
#pragma unroll
    for (int m = 1; m < 64; m <<= 1) se += __shfl_xor(se, m, 64);
    if (lane == 0) wsum[wave] = se;
    __syncthreads();
    const float inv = 1.0f / (wsum[0] + wsum[1] + wsum[2] + wsum[3]);

    // PV: 8 threads per output dim; each reads a contiguous 64-key V span.
    const int d = tid >> 3, seg = tid & 7;
    const bf16* vr = &vT[((size_t)(b * 8 + hh) * 32 + d) * 512 + seg * 64];
    const float* pp = &p_lds[seg * 64];
    float o = 0.0f;
#pragma unroll
    for (int i = 0; i < 64; i += 8) {
        bf16x8 vv = *(const bf16x8*)&vr[i];
#pragma unroll
        for (int q = 0; q < 8; q++) o += pp[i + q] * (float)vv[q];
    }
#pragma unroll
    for (int m = 1; m < 8; m <<= 1) o += __shfl_xor(o, m, 64);
    if (seg == 0) pattn[b * 256 + hh * 32 + d] = o * inv;
}

// ---------------------------------------------------------------------------
// Heads tail: action head on waves 0-1 (threads 0-127) CONCURRENT with
// profit head on waves 2-3 (threads 128-255). LN via per-wave shuffle reduce
// + one 8-float LDS exchange (1 barrier each). All __syncthreads are
// straight-line (reached by all 256 threads). grid 16, block 256.
// ---------------------------------------------------------------------------
__global__ __launch_bounds__(256) void heads_kernel(
    const float* __restrict__ pattn,
    const bf16* __restrict__ pout_w, const bf16* __restrict__ pout_b,
    const bf16* __restrict__ aw1, const bf16* __restrict__ ab1,
    const bf16* __restrict__ aln1s, const bf16* __restrict__ aln1b,
    const bf16* __restrict__ aw2, const bf16* __restrict__ ab2,
    const bf16* __restrict__ aln2s, const bf16* __restrict__ aln2b,
    const bf16* __restrict__ aw3, const bf16* __restrict__ ab3,
    const bf16* __restrict__ pw1, const bf16* __restrict__ pb1,
    const bf16* __restrict__ pln1s, const bf16* __restrict__ pln1b,
    const bf16* __restrict__ pw2, const bf16* __restrict__ pb2,
    const bf16* __restrict__ pln2s, const bf16* __restrict__ pln2b,
    const bf16* __restrict__ pw3, const bf16* __restrict__ pb3,
    float* __restrict__ out) {
    const int b = blockIdx.x, t = threadIdx.x;
    const int wave = t >> 6, lane = t & 63;
    __shared__ float pa_s[256], pool[256];
    __shared__ float bufa[128], buf2a[64];
    __shared__ float bufp[256], buf2p[128];
    __shared__ float red[8];

    pa_s[t] = pattn[b * 256 + t];
    __syncthreads();

    // ---- phase 0: pooled projection (all 256 threads) ----
    {
        float a = (float)pout_b[t];
        const bf16* wr = &pout_w[t * 256];
        for (int k = 0; k < 256; k += 8) {
            bf16x8 wv = *(const bf16x8*)&wr[k];
#pragma unroll
            for (int q = 0; q < 8; q++) a += pa_s[k + q] * (float)wv[q];
        }
        pool[t] = a;
    }
    __syncthreads();

    // ---- phase 1: first linears (action || profit) ----
    if (t < 128) {
        float a = (float)ab1[t];
        const bf16* wr = &aw1[t * 256];
        for (int k = 0; k < 256; k += 8) {
            bf16x8 wv = *(const bf16x8*)&wr[k];
#pragma unroll
            for (int q = 0; q < 8; q++) a += pool[k + q] * (float)wv[q];
        }
        bufa[t] = gelu_exact(a);
    } else {
        const int u = t - 128;
        float a0 = (float)pb1[u], a1 = (float)pb1[u + 128];
        const bf16* w0 = &pw1[u * 256];
        const bf16* w1 = &pw1[(u + 128) * 256];
        for (int k = 0; k < 256; k += 8) {
            bf16x8 wv0 = *(const bf16x8*)&w0[k];
            bf16x8 wv1 = *(const bf16x8*)&w1[k];
#pragma unroll
            for (int q = 0; q < 8; q++) {
                const float pv = pool[k + q];
                a0 += pv * (float)wv0[q];
                a1 += pv * (float)wv1[q];
            }
        }
        bufp[u] = a0;
        bufp[u + 128] = a1;
    }
    __syncthreads();

    // ---- phase 2: LN1 (action W=128 || profit W=256), shuffle reduce ----
    {
        float s1, s2;
        if (t < 128) {
            const float v = bufa[t];
            s1 = v; s2 = v * v;
        } else {
            const int u = t - 128;
            const float v0 = bufp[u], v1 = bufp[u + 128];
            s1 = v0 + v1; s2 = v0 * v0 + v1 * v1;
        }
#pragma unroll
        for (int m = 1; m < 64; m <<= 1) {
            s1 += __shfl_xor(s1, m, 64);
            s2 += __shfl_xor(s2, m, 64);
        }
        if (lane == 0) { red[wave * 2] = s1; red[wave * 2 + 1] = s2; }
    }
    __syncthreads();
    if (t < 128) {
        const float S1 = red[0] + red[2], S2 = red[1] + red[3];
        const float mean = S1 * (1.0f / 128.0f);
        const float var = fmaxf(S2 * (1.0f / 128.0f) - mean * mean, 0.0f);
        const float inv = rsqrtf(var + 1e-5f);
        bufa[t] = (bufa[t] - mean) * inv * (float)aln1s[t] + (float)aln1b[t];
    } else {
        const int u = t - 128;
        const float S1 = red[4] + red[6], S2 = red[5] + red[7];
        const float mean = S1 * (1.0f / 256.0f);
        const float var = fmaxf(S2 * (1.0f / 256.0f) - mean * mean, 0.0f);
        const float inv = rsqrtf(var + 1e-5f);
        bufp[u] = gelu_exact((bufp[u] - mean) * inv * (float)pln1s[u] + (float)pln1b[u]);
        bufp[u + 128] = gelu_exact((bufp[u + 128] - mean) * inv *
                                   (float)pln1s[u + 128] + (float)pln1b[u + 128]);
    }
    __syncthreads();

    // ---- phase 3: second linears ----
    if (t < 64) {
        float a = (float)ab2[t];
        const bf16* wr = &aw2[t * 128];
        for (int k = 0; k < 128; k += 8) {
            bf16x8 wv = *(const bf16x8*)&wr[k];
#pragma unroll
            for (int q = 0; q < 8; q++) a += bufa[k + q] * (float)wv[q];
        }
        buf2a[t] = gelu_exact(a);
    } else if (t >= 128) {
        const int u = t - 128;
        float a = (float)pb2[u];
        const bf16* wr = &pw2[u * 256];
        for (int k = 0; k < 256; k += 8) {
            bf16x8 wv = *(const bf16x8*)&wr[k];
#pragma unroll
            for (int q = 0; q < 8; q++) a += bufp[k + q] * (float)wv[q];
        }
        buf2p[u] = a;
    }
    __syncthreads();

    // ---- phase 4: LN2 (action W=64 in wave0 || profit W=128), shuffle ----
    {
        float s1 = 0.0f, s2 = 0.0f;
        if (t < 64) {
            const float v = buf2a[t];
            s1 = v; s2 = v * v;
        } else if (t >= 128) {
            const float v = buf2p[t - 128];
            s1 = v; s2 = v * v;
        }
#pragma unroll
        for (int m = 1; m < 64; m <<= 1) {
            s1 += __shfl_xor(s1, m, 64);
            s2 += __shfl_xor(s2, m, 64);
        }
        if (lane == 0) { red[wave * 2] = s1; red[wave * 2 + 1] = s2; }
    }
    __syncthreads();
    if (t < 64) {
        const float S1 = red[0], S2 = red[1];
        const float mean = S1 * (1.0f / 64.0f);
        const float var = fmaxf(S2 * (1.0f / 64.0f) - mean * mean, 0.0f);
        const float inv = rsqrtf(var + 1e-5f);
        buf2a[t] = (buf2a[t] - mean) * inv * (float)aln2s[t] + (float)aln2b[t];
    } else if (t >= 128) {
        const int u = t - 128;
        const float S1 = red[4] + red[6], S2 = red[5] + red[7];
        const float mean = S1 * (1.0f / 128.0f);
        const float var = fmaxf(S2 * (1.0f / 128.0f) - mean * mean, 0.0f);
        const float inv = rsqrtf(var + 1e-5f);
        buf2p[u] = gelu_exact((buf2p[u] - mean) * inv *
                              (float)pln2s[u] + (float)pln2b[u]);
    }
    __syncthreads();

    // ---- phase 5: finals ----
    if (t < 3) {
        float a = (float)ab3[t];
        for (int k = 0; k < 64; k++) a += buf2a[k] * (float)aw3[t * 64 + k];
        out[b * 3 + t] = a;
    }
    {
        float p = 0.0f;
        if (t >= 128) p = buf2p[t - 128] * (float)pw3[t - 128];
#pragma unroll
        for (int m = 1; m < 64; m <<= 1) p += __shfl_xor(p, m, 64);
        if (lane == 0) red[wave] = p;
    }
    __syncthreads();
    if (t == 0) out[48 + b] = (float)pb3[0] + red[2] + red[3];
}

// ---------------------------------------------------------------------------
extern "C" void kernel_launch(void* const* d_in, const int* in_sizes, int n_in,
                              void* d_out, int out_size, void* d_ws, size_t ws_size,
                              hipStream_t stream) {
    char* ws = (char*)d_ws;
    const size_t MB = 1024 * 1024;
    bf16*  h     = (bf16*)(ws);                        // 8193x256
    bf16*  moe0  = (bf16*)(ws + 8 * MB);               // 8193x256
    bf16*  moe1  = (bf16*)(ws + 13 * MB);              // 8193x256
    char*  ctrl  = ws + 20 * MB;
    float* auxs   = (float*)(ctrl + 0);                // 48 f32
    int*   flag   = (int*)(ctrl + 192);
    int*   ntiles = (int*)(ctrl + 256);                // [2]
    int*   tileex = (int*)(ctrl + 320);                // [2][72]
    float* ostage = (float*)(ctrl + 1024);             // 65 f32
    int*   g_hist = (int*)(ctrl + 2048);               // [512][16] = 32 KB
    int*   top_e  = (int*)(ctrl + 36864);              // [2][8192]
    float* top_w  = (float*)(ctrl + 102400);           // [2][8192]
    int*   list   = (int*)(ctrl + 167936);             // [2][9216]
    float* lw     = (float*)(ctrl + 241664);           // [2][9216]
    bf16*  qkv   = (bf16*)(ws + 24 * MB);              // 8192x768
    bf16*  aoutb = (bf16*)(ws + 40 * MB);              // 8192x256
    bf16*  projtmp = (bf16*)(ws + 46 * MB);            // 8192x256 (4 MB)
    bf16*  hid0  = (bf16*)(ws + 56 * MB);              // 9216x1024
    bf16*  hid1  = (bf16*)(ws + 80 * MB);              // 9216x1024
    bf16*  vT    = (bf16*)(ws + 104 * MB);             // [16][8][32][512]
    float* pattn = (float*)(ws + 110 * MB);            // 16x256 f32
    bf16*  cvbase = (bf16*)(ws + 112 * MB);            // ~10.6 MB

    InTab tab;
    unsigned off = 0;
    bf16* cv[NIN];
    for (int i = 0; i < NIN; i++) {
        tab.src[i] = d_in[i];
        tab.off[i] = off;
        tab.n[i] = (unsigned)in_sizes[i];
        cv[i] = cvbase + off;
        off += ((unsigned)in_sizes[i] + 1023u) & ~1023u;
    }
    const int cv_blocks = (int)(off >> 10);

    const bf16 *x = cv[0], *in_w = cv[1], *in_b = cv[2], *qkv_w = cv[3], *qkv_b = cv[4],
               *out_w = cv[5], *out_b = cv[6], *gate_w = cv[7], *gate_b = cv[8],
               *e_w1 = cv[9], *e_b1 = cv[10], *e_w2 = cv[11], *e_b2 = cv[12],
               *ln1_s = cv[13], *ln1_b = cv[14], *ln2_s = cv[15], *ln2_b = cv[16],
               *pqkv_w = cv[17], *pqkv_b = cv[18], *pout_w = cv[19], *pout_b = cv[20],
               *a_w1 = cv[21], *a_b1 = cv[22], *a_ln1s = cv[23], *a_ln1b = cv[24],
               *a_w2 = cv[25], *a_b2 = cv[26], *a_ln2s = cv[27], *a_ln2b = cv[28],
               *a_w3 = cv[29], *a_b3 = cv[30],
               *pr_w1 = cv[31], *pr_b1 = cv[32], *pr_ln1s = cv[33], *pr_ln1b = cv[34],
               *pr_w2 = cv[35], *pr_b2 = cv[36], *pr_ln2s = cv[37], *pr_ln2b = cv[38],
               *pr_w3 = cv[39], *pr_b3 = cv[40];

    sniff_kernel<<<1, 256, 0, stream>>>((const unsigned*)d_in[0], flag);
    convert_kernel<<<cv_blocks, 256, 0, stream>>>(tab, cvbase, flag);

    hipMemsetAsync(auxs, 0, 192, stream);
    // zero the padding-token row h[8192] (read via list for padded slots)
    hipMemsetAsync((char*)h + (size_t)8192 * 512, 0, 512, stream);
    input_proj_kernel<<<8192, 256, 0, stream>>>(x, in_w, in_b, h);

    for (int l = 0; l < 6; l++) {
        gemm_bt<64, 128, 32, 64, true><<<dim3(128, 6), 256, 0, stream>>>(
            h, qkv_w, qkv_b, qkv, 8192, 768, 256, vT, 0);
        attn_kernel<<<dim3(16, 128), 256, 0, stream>>>(qkv, vT, aoutb);
        gemm_bt<32, 64, 16, 32, false><<<dim3(256, 4), 256, 0, stream>>>(
            aoutb, out_w, out_b, projtmp, 8192, 256, 256, nullptr, 0);
        ln_gate_kernel<<<512, 256, 0, stream>>>(
            projtmp, h, ln1_s, ln1_b, gate_w, gate_b,
            top_e, top_w, g_hist, auxs + l * 8);
        scatter_route_kernel<<<64, 256, 0, stream>>>(g_hist, top_e, top_w,
                                                     ntiles, tileex, list, lw);
        gemm_moe_w1<<<dim3(288, 8), 256, 0, stream>>>(
            h, e_w1, e_b1, hid0, hid1, list, tileex, ntiles);
        gemm_moe_w2<<<dim3(288, 4), 256, 0, stream>>>(
            hid0, hid1, e_w2, e_b2, moe0, moe1, list, lw, tileex, ntiles);
        ln_kernel<<<1024, 256, 0, stream>>>(h, moe0, moe1, ln2_s, ln2_b);
    }

    // final projection: K+V only (cols 256..767); Q computed in pooled_attn
    gemm_bt<64, 128, 32, 64, true><<<dim3(128, 4), 256, 0, stream>>>(
        h, pqkv_w, pqkv_b, qkv, 8192, 768, 256, vT, 256);
    pooled_attn_kernel<<<128, 256, 0, stream>>>(qkv, vT, h, pqkv_w, pqkv_b, pattn);
    heads_kernel<<<16, 256, 0, stream>>>(
        pattn, pout_w, pout_b,
        a_w1, a_b1, a_ln1s, a_ln1b, a_w2, a_b2, a_ln2s, a_ln2b, a_w3, a_b3,
        pr_w1, pr_b1, pr_ln1s, pr_ln1b, pr_w2, pr_b2, pr_ln2s, pr_ln2b, pr_w3, pr_b3,
        ostage);
    out_convert_kernel<<<1, 128, 0, stream>>>(ostage, auxs, d_out, flag);
}